// Round 1
// baseline (193.057 us; speedup 1.0000x reference)
//
#include <hip/hip_runtime.h>

#define B_ 8
#define HI 256
#define WI 256
#define HO 1024
#define WO 1024

// ---------------- tap table: idx[4] + Keys cubic weights[4] per output coord ----------------
__global__ void k_taps(int4* __restrict__ tidx, float4* __restrict__ twgt) {
    int j = blockIdx.x * blockDim.x + threadIdx.x;
    if (j >= HO) return;
    const float a = -0.75f;
    float src = (float)j * ((float)(HI - 1) / (float)(HO - 1));
    float fi0 = floorf(src);
    float t = src - fi0;
    float t1 = t + 1.0f;
    float w0 = ((a * t1 - 5.0f * a) * t1 + 8.0f * a) * t1 - 4.0f * a;
    float w1 = ((a + 2.0f) * t - (a + 3.0f)) * t * t + 1.0f;
    float u = 1.0f - t;
    float w2 = ((a + 2.0f) * u - (a + 3.0f)) * u * u + 1.0f;
    float u2 = 2.0f - t;
    float w3 = ((a * u2 - 5.0f * a) * u2 + 8.0f * a) * u2 - 4.0f * a;
    int i0 = (int)fi0;
    int4 id;
    id.x = min(max(i0 - 1, 0), HI - 1);
    id.y = min(max(i0,     0), HI - 1);
    id.z = min(max(i0 + 1, 0), HI - 1);
    id.w = min(max(i0 + 2, 0), HI - 1);
    tidx[j] = id;
    twgt[j] = make_float4(w0, w1, w2, w3);
}

// ---------------- sigmoid, float4-vectorized ----------------
__global__ void k_sigmoid(const float4* __restrict__ in, float4* __restrict__ out, int n4) {
    int i = blockIdx.x * blockDim.x + threadIdx.x;
    if (i >= n4) return;
    float4 v = in[i];
    v.x = 1.0f / (1.0f + __expf(-v.x));
    v.y = 1.0f / (1.0f + __expf(-v.y));
    v.z = 1.0f / (1.0f + __expf(-v.z));
    v.w = 1.0f / (1.0f + __expf(-v.w));
    out[i] = v;
}

// ---------------- bicubic 256 -> 1024, 16-tap gather ----------------
__global__ void k_resize(const float* __restrict__ sig, const int4* __restrict__ tidx,
                         const float4* __restrict__ twgt, float* __restrict__ out) {
    int x = blockIdx.x * blockDim.x + threadIdx.x;
    int y = blockIdx.y;
    int b = blockIdx.z;
    int4 ry = tidx[y];       // uniform across block -> scalar loads
    float4 wy = twgt[y];
    int4 cx = tidx[x];
    float4 wx = twgt[x];
    const float* p = sig + b * (HI * WI);
    const float* r0 = p + ry.x * WI;
    const float* r1 = p + ry.y * WI;
    const float* r2 = p + ry.z * WI;
    const float* r3 = p + ry.w * WI;
    float s0 = wx.x * r0[cx.x] + wx.y * r0[cx.y] + wx.z * r0[cx.z] + wx.w * r0[cx.w];
    float s1 = wx.x * r1[cx.x] + wx.y * r1[cx.y] + wx.z * r1[cx.z] + wx.w * r1[cx.w];
    float s2 = wx.x * r2[cx.x] + wx.y * r2[cx.y] + wx.z * r2[cx.z] + wx.w * r2[cx.w];
    float s3 = wx.x * r3[cx.x] + wx.y * r3[cx.y] + wx.z * r3[cx.z] + wx.w * r3[cx.w];
    float acc = wy.x * s0 + wy.y * s1 + wy.z * s2 + wy.w * s3;
    out[(size_t)(b * HO + y) * WO + x] = acc;
}

// ---------------- 3x3 Gaussian, sigma=1, zero padding ----------------
__global__ void k_smooth(const float* __restrict__ in, float* __restrict__ out) {
    int x = blockIdx.x * blockDim.x + threadIdx.x;
    int y = blockIdx.y;
    int b = blockIdx.z;
    const float wv[3] = {0.27406862f, 0.45186276f, 0.27406862f};
    const float* p = in + (size_t)b * HO * WO;
    float acc = 0.0f;
#pragma unroll
    for (int dy = -1; dy <= 1; ++dy) {
        int yy = y + dy;
        if (yy < 0 || yy >= HO) continue;
        const float* rp = p + (size_t)yy * WO;
        float rs = 0.0f;
#pragma unroll
        for (int dx = -1; dx <= 1; ++dx) {
            int xx = x + dx;
            float v = (xx >= 0 && xx < WO) ? rp[xx] : 0.0f;
            rs += wv[dx + 1] * v;
        }
        acc += wv[dy + 1] * rs;
    }
    out[(size_t)(b * HO + y) * WO + x] = acc;
}

// ---------------- one soft-dilate iteration (zero pad -> OOB tap = exp(-5)) ----------------
__global__ void k_dilate(const float* __restrict__ in, float* __restrict__ out) {
    int x = blockIdx.x * blockDim.x + threadIdx.x;
    int y = blockIdx.y;
    int b = blockIdx.z;
    const float* p = in + (size_t)b * HO * WO;
    float s = 0.0f;
#pragma unroll
    for (int dy = -1; dy <= 1; ++dy) {
        int yy = y + dy;
#pragma unroll
        for (int dx = -1; dx <= 1; ++dx) {
            int xx = x + dx;
            float v = (yy >= 0 && yy < HO && xx >= 0 && xx < WO) ? p[(size_t)yy * WO + xx] : 0.0f;
            s += __expf(5.0f * (v - 1.0f));
        }
    }
    float r = 1.0f + 0.2f * __logf(s);
    out[(size_t)(b * HO + y) * WO + x] = fminf(fmaxf(r, 0.0f), 1.0f);
}

extern "C" void kernel_launch(void* const* d_in, const int* in_sizes, int n_in,
                              void* d_out, int out_size, void* d_ws, size_t ws_size,
                              hipStream_t stream) {
    const float* in = (const float*)d_in[0];
    float* out = (float*)d_out;

    // workspace layout: sigmoid (2MB) | idx table (16KB) | weight table (16KB) | big ping (32MB)
    float* sig  = (float*)d_ws;
    int4*  tidx = (int4*)(sig + B_ * HI * WI);
    float4* twgt = (float4*)((int*)tidx + 4 * HO);
    float* big  = (float*)((float*)twgt + 4 * HO);

    k_taps<<<dim3((HO + 255) / 256), dim3(256), 0, stream>>>(tidx, twgt);

    int n4 = B_ * HI * WI / 4;                         // 131072
    k_sigmoid<<<dim3(n4 / 256), dim3(256), 0, stream>>>((const float4*)in, (float4*)sig, n4);

    dim3 g(WO / 256, HO, B_);
    k_resize<<<g, dim3(256), 0, stream>>>(sig, tidx, twgt, big);   // big = resized
    k_smooth<<<g, dim3(256), 0, stream>>>(big, out);               // out = smoothed
    k_dilate<<<g, dim3(256), 0, stream>>>(out, big);               // big = dilate1
    k_dilate<<<g, dim3(256), 0, stream>>>(big, out);               // out = dilate2 (final)
}

// Round 2
// 81.157 us; speedup vs baseline: 2.3788x; 2.3788x over previous
//
#include <hip/hip_runtime.h>

#define B_ 8
#define HI 256
#define WI 256
#define HO 1024
#define WO 1024

#define TILE 32
#define HALO 3
#define RSZ  (TILE + 2 * HALO)   // 38
#define LSTR (RSZ + 1)           // 39, odd stride -> conflict-free

// ---------------- tap table: idx[4] + Keys cubic weights[4] per output coord ----------------
__global__ void k_taps(int4* __restrict__ tidx, float4* __restrict__ twgt) {
    int j = blockIdx.x * blockDim.x + threadIdx.x;
    if (j >= HO) return;
    const float a = -0.75f;
    float src = (float)j * ((float)(HI - 1) / (float)(HO - 1));
    float fi0 = floorf(src);
    float t = src - fi0;
    float t1 = t + 1.0f;
    float w0 = ((a * t1 - 5.0f * a) * t1 + 8.0f * a) * t1 - 4.0f * a;
    float w1 = ((a + 2.0f) * t - (a + 3.0f)) * t * t + 1.0f;
    float u = 1.0f - t;
    float w2 = ((a + 2.0f) * u - (a + 3.0f)) * u * u + 1.0f;
    float u2 = 2.0f - t;
    float w3 = ((a * u2 - 5.0f * a) * u2 + 8.0f * a) * u2 - 4.0f * a;
    int i0 = (int)fi0;
    int4 id;
    id.x = min(max(i0 - 1, 0), HI - 1);
    id.y = min(max(i0,     0), HI - 1);
    id.z = min(max(i0 + 1, 0), HI - 1);
    id.w = min(max(i0 + 2, 0), HI - 1);
    tidx[j] = id;
    twgt[j] = make_float4(w0, w1, w2, w3);
}

// ---------------- sigmoid, float4-vectorized ----------------
__global__ void k_sigmoid(const float4* __restrict__ in, float4* __restrict__ out, int n4) {
    int i = blockIdx.x * blockDim.x + threadIdx.x;
    if (i >= n4) return;
    float4 v = in[i];
    v.x = 1.0f / (1.0f + __expf(-v.x));
    v.y = 1.0f / (1.0f + __expf(-v.y));
    v.z = 1.0f / (1.0f + __expf(-v.z));
    v.w = 1.0f / (1.0f + __expf(-v.w));
    out[i] = v;
}

// ---------------- fused resize -> smooth -> dilate -> dilate ----------------
// One 32x32 output tile per block. All intermediates live in LDS with a
// 3-deep halo; out-of-image coords are 0 at every stage (zero padding).
__global__ __launch_bounds__(256) void k_fused(const float* __restrict__ sig,
                                               const int4* __restrict__ tidx,
                                               const float4* __restrict__ twgt,
                                               float* __restrict__ out) {
    __shared__ float A[RSZ * LSTR];
    __shared__ float Bf[RSZ * LSTR];
    const int tid = threadIdx.x;
    const int bx = blockIdx.x, by = blockIdx.y, b = blockIdx.z;
    const float* p = sig + b * (HI * WI);
    const int oy0 = by * TILE - HALO;   // global coord of A[0][*]
    const int ox0 = bx * TILE - HALO;

    // Stage A: bicubic resize into A (38x38)
    for (int i = tid; i < RSZ * RSZ; i += 256) {
        int ly = i / RSZ, lx = i % RSZ;
        int gy = oy0 + ly, gx = ox0 + lx;
        float v = 0.0f;
        if ((unsigned)gy < HO && (unsigned)gx < WO) {
            int4 iy = tidx[gy]; float4 wy = twgt[gy];
            int4 ix = tidx[gx]; float4 wx = twgt[gx];
            const float* r0 = p + iy.x * WI;
            const float* r1 = p + iy.y * WI;
            const float* r2 = p + iy.z * WI;
            const float* r3 = p + iy.w * WI;
            float s0 = wx.x * r0[ix.x] + wx.y * r0[ix.y] + wx.z * r0[ix.z] + wx.w * r0[ix.w];
            float s1 = wx.x * r1[ix.x] + wx.y * r1[ix.y] + wx.z * r1[ix.z] + wx.w * r1[ix.w];
            float s2 = wx.x * r2[ix.x] + wx.y * r2[ix.y] + wx.z * r2[ix.z] + wx.w * r2[ix.w];
            float s3 = wx.x * r3[ix.x] + wx.y * r3[ix.y] + wx.z * r3[ix.z] + wx.w * r3[ix.w];
            v = wy.x * s0 + wy.y * s1 + wy.z * s2 + wy.w * s3;
        }
        A[ly * LSTR + lx] = v;
    }
    __syncthreads();

    // Stage B: 3x3 Gaussian into Bf, region [1..36]^2
    {
        const float w0 = 0.27406862f, w1 = 0.45186276f;
        for (int i = tid; i < 36 * 36; i += 256) {
            int ly = 1 + i / 36, lx = 1 + i % 36;
            int gy = oy0 + ly, gx = ox0 + lx;
            float v = 0.0f;
            if ((unsigned)gy < HO && (unsigned)gx < WO) {
                const float* a = &A[(ly - 1) * LSTR + (lx - 1)];
                float r0 = w0 * a[0]        + w1 * a[1]            + w0 * a[2];
                float r1 = w0 * a[LSTR]     + w1 * a[LSTR + 1]     + w0 * a[LSTR + 2];
                float r2 = w0 * a[2 * LSTR] + w1 * a[2 * LSTR + 1] + w0 * a[2 * LSTR + 2];
                v = w0 * r0 + w1 * r1 + w0 * r2;
            }
            Bf[ly * LSTR + lx] = v;
        }
    }
    __syncthreads();

    // Stage C: soft-dilate #1 from Bf into A, region [2..35]^2
    for (int i = tid; i < 34 * 34; i += 256) {
        int ly = 2 + i / 34, lx = 2 + i % 34;
        int gy = oy0 + ly, gx = ox0 + lx;
        float v = 0.0f;
        if ((unsigned)gy < HO && (unsigned)gx < WO) {
            const float* a = &Bf[(ly - 1) * LSTR + (lx - 1)];
            float s = 0.0f;
#pragma unroll
            for (int dy = 0; dy < 3; ++dy)
#pragma unroll
                for (int dx = 0; dx < 3; ++dx)
                    s += __expf(5.0f * (a[dy * LSTR + dx] - 1.0f));
            v = fminf(fmaxf(1.0f + 0.2f * __logf(s), 0.0f), 1.0f);
        }
        A[ly * LSTR + lx] = v;
    }
    __syncthreads();

    // Stage D: soft-dilate #2 from A, write 32x32 tile to global
    for (int i = tid; i < TILE * TILE; i += 256) {
        int ly = HALO + i / TILE, lx = HALO + i % TILE;
        const float* a = &A[(ly - 1) * LSTR + (lx - 1)];
        float s = 0.0f;
#pragma unroll
        for (int dy = 0; dy < 3; ++dy)
#pragma unroll
            for (int dx = 0; dx < 3; ++dx)
                s += __expf(5.0f * (a[dy * LSTR + dx] - 1.0f));
        float v = fminf(fmaxf(1.0f + 0.2f * __logf(s), 0.0f), 1.0f);
        int gy = oy0 + ly, gx = ox0 + lx;
        out[((size_t)b * HO + gy) * WO + gx] = v;
    }
}

extern "C" void kernel_launch(void* const* d_in, const int* in_sizes, int n_in,
                              void* d_out, int out_size, void* d_ws, size_t ws_size,
                              hipStream_t stream) {
    const float* in = (const float*)d_in[0];
    float* out = (float*)d_out;

    // workspace layout: sigmoid (2MB) | idx table (16KB) | weight table (16KB)
    float* sig   = (float*)d_ws;
    int4*  tidx  = (int4*)(sig + B_ * HI * WI);
    float4* twgt = (float4*)((int*)tidx + 4 * HO);

    k_taps<<<dim3((HO + 255) / 256), dim3(256), 0, stream>>>(tidx, twgt);

    int n4 = B_ * HI * WI / 4;
    k_sigmoid<<<dim3(n4 / 256), dim3(256), 0, stream>>>((const float4*)in, (float4*)sig, n4);

    dim3 g(WO / TILE, HO / TILE, B_);   // (32, 32, 8)
    k_fused<<<g, dim3(256), 0, stream>>>(sig, tidx, twgt, out);
}

// Round 3
// 79.856 us; speedup vs baseline: 2.4176x; 1.0163x over previous
//
#include <hip/hip_runtime.h>

#define B_ 8
#define HI 256
#define WI 256
#define HO 1024
#define WO 1024

#define T 64
#define HALO 3
#define FR (T + 2 * HALO)     // 70 frame
#define FSTR (FR + 1)         // 71 odd stride -> conflict-free
#define NEXT (HO + 2 * HALO)  // 1030 extended table entries (gy in [-3, 1027))
#define EXPM5 0.0067379470f   // exp(-5), the soft-dilate zero-pad value in E-space

// ---- extended tap tables: entry j corresponds to output coord g = j-3 (clamped for OOB) ----
__global__ void k_taps(int4* __restrict__ tidx, float4* __restrict__ twgt) {
    int j = blockIdx.x * blockDim.x + threadIdx.x;
    if (j >= NEXT) return;
    int g = j - HALO;
    int gc = min(max(g, 0), HO - 1);
    const float a = -0.75f;
    float src = (float)gc * ((float)(HI - 1) / (float)(HO - 1));
    float fi0 = floorf(src);
    float t = src - fi0;
    float t1 = t + 1.0f;
    float w0 = ((a * t1 - 5.0f * a) * t1 + 8.0f * a) * t1 - 4.0f * a;
    float w1 = ((a + 2.0f) * t - (a + 3.0f)) * t * t + 1.0f;
    float u = 1.0f - t;
    float w2 = ((a + 2.0f) * u - (a + 3.0f)) * u * u + 1.0f;
    float u2 = 2.0f - t;
    float w3 = ((a * u2 - 5.0f * a) * u2 + 8.0f * a) * u2 - 4.0f * a;
    int i0 = (int)fi0;
    int4 id;
    id.x = min(max(i0 - 1, 0), HI - 1);
    id.y = min(max(i0,     0), HI - 1);
    id.z = min(max(i0 + 1, 0), HI - 1);
    id.w = min(max(i0 + 2, 0), HI - 1);
    tidx[j] = id;
    twgt[j] = make_float4(w0, w1, w2, w3);
}

__global__ void k_sigmoid(const float4* __restrict__ in, float4* __restrict__ out, int n4) {
    int i = blockIdx.x * blockDim.x + threadIdx.x;
    if (i >= n4) return;
    float4 v = in[i];
    v.x = 1.0f / (1.0f + __expf(-v.x));
    v.y = 1.0f / (1.0f + __expf(-v.y));
    v.z = 1.0f / (1.0f + __expf(-v.z));
    v.w = 1.0f / (1.0f + __expf(-v.w));
    out[i] = v;
}

// ---- fused: separable bicubic -> separable gaussian -> E1 -> boxsum/min -> boxsum/log ----
// block = (64,4); one 64x64 output tile per block. All stencils separable; each
// dilate needs only 1 transcendental per pixel (dilate#1's exp(clip(log..)) == min(S,1)).
__global__ __launch_bounds__(256) void k_fused(const float* __restrict__ sig,
                                               const int4* __restrict__ tidx,
                                               const float4* __restrict__ twgt,
                                               float* __restrict__ out) {
    __shared__ float A[FR * FSTR];
    __shared__ float Bf[FR * FSTR];
    float* hres = Bf;  // alias: horizontal-resize scratch, dead before Bf's first real use

    const int tx = threadIdx.x, ty = threadIdx.y;
    const int bx = blockIdx.x, by = blockIdx.y, b = blockIdx.z;
    const int oy0 = by * T - HALO, ox0 = bx * T - HALO;
    const float* p = sig + b * (HI * WI);

    // contiguous input-row range this tile touches (tables are monotone)
    const int rlo = tidx[by * T].x;
    const int rhi = tidx[by * T + FR - 1].w;
    const int nrows = rhi - rlo + 1;  // <= 22

    // Stage 1a: horizontal bicubic on needed input rows -> hres[nrows][70]
    for (int y = ty; y < nrows; y += 4) {
        const float* row = p + (rlo + y) * WI;
        for (int x = tx; x < FR; x += 64) {
            int4 ix = tidx[bx * T + x];
            float4 wx = twgt[bx * T + x];
            hres[y * FSTR + x] = wx.x * row[ix.x] + wx.y * row[ix.y] +
                                 wx.z * row[ix.z] + wx.w * row[ix.w];
        }
    }
    __syncthreads();

    // Stage 1b: vertical bicubic -> A[70][70]; zero outside image (conv zero-pad)
    for (int y = ty; y < FR; y += 4) {
        int4 iy = tidx[by * T + y];          // wave-uniform
        float4 wy = twgt[by * T + y];
        const float* h0 = hres + (iy.x - rlo) * FSTR;
        const float* h1 = hres + (iy.y - rlo) * FSTR;
        const float* h2 = hres + (iy.z - rlo) * FSTR;
        const float* h3 = hres + (iy.w - rlo) * FSTR;
        bool yok = (unsigned)(oy0 + y) < HO;
        for (int x = tx; x < FR; x += 64) {
            float v = wy.x * h0[x] + wy.y * h1[x] + wy.z * h2[x] + wy.w * h3[x];
            if (!yok || (unsigned)(ox0 + x) >= WO) v = 0.0f;
            A[y * FSTR + x] = v;
        }
    }
    __syncthreads();

    const float w0 = 0.27406862f, w1 = 0.45186276f;

    // Stage 2a: horizontal gaussian -> Bf, x in [1,69)
    for (int y = ty; y < FR; y += 4)
        for (int x = 1 + tx; x < FR - 1; x += 64) {
            const float* a = A + y * FSTR + x;
            Bf[y * FSTR + x] = w0 * (a[-1] + a[1]) + w1 * a[0];
        }
    __syncthreads();

    // Stage 2b+3a: vertical gaussian + E1 = exp(5*smooth-5) -> A, region [1,69)^2
    // OOB positions get the pad value exp(-5).
    for (int y = 1 + ty; y < FR - 1; y += 4) {
        bool yok = (unsigned)(oy0 + y) < HO;
        for (int x = 1 + tx; x < FR - 1; x += 64) {
            const float* bp = Bf + y * FSTR + x;
            float sm = w0 * (bp[-FSTR] + bp[FSTR]) + w1 * bp[0];
            float e = __expf(fmaf(5.0f, sm, -5.0f));
            if (!yok || (unsigned)(ox0 + x) >= WO) e = EXPM5;
            A[y * FSTR + x] = e;
        }
    }
    __syncthreads();

    // Stage 3b: row sums of E1 -> Bf, y in [1,69), x in [2,68)
    for (int y = 1 + ty; y < FR - 1; y += 4)
        for (int x = 2 + tx; x < FR - 2; x += 64) {
            const float* a = A + y * FSTR + x;
            Bf[y * FSTR + x] = a[-1] + a[0] + a[1];
        }
    __syncthreads();

    // Stage 3c+4a: E2 = min(col-sum, 1) -> A, region [2,68)^2
    // (dilate#1: exp(5*clip(1+ln(S)/5,0,1)-5) == min(S,1); lower clip never fires)
    for (int y = 2 + ty; y < FR - 2; y += 4) {
        bool yok = (unsigned)(oy0 + y) < HO;
        for (int x = 2 + tx; x < FR - 2; x += 64) {
            const float* bp = Bf + y * FSTR + x;
            float v = fminf(bp[-FSTR] + bp[0] + bp[FSTR], 1.0f);
            if (!yok || (unsigned)(ox0 + x) >= WO) v = EXPM5;
            A[y * FSTR + x] = v;
        }
    }
    __syncthreads();

    // Stage 4b: row sums of E2 -> Bf, y in [2,68), x in [3,67)
    for (int y = 2 + ty; y < FR - 2; y += 4)
        for (int x = 3 + tx; x < FR - 3; x += 64) {
            const float* a = A + y * FSTR + x;
            Bf[y * FSTR + x] = a[-1] + a[0] + a[1];
        }
    __syncthreads();

    // Stage 4c: out = clamp(1 + 0.2*ln(col-sum), 0, 1), write 64x64 tile
    for (int y = 3 + ty; y < FR - 3; y += 4) {
        int gy = oy0 + y;
        for (int x = 3 + tx; x < FR - 3; x += 64) {
            const float* bp = Bf + y * FSTR + x;
            float s = bp[-FSTR] + bp[0] + bp[FSTR];
            float r = fminf(fmaf(0.2f, __logf(s), 1.0f), 1.0f);
            out[((size_t)b * HO + gy) * WO + (ox0 + x)] = fmaxf(r, 0.0f);
        }
    }
}

extern "C" void kernel_launch(void* const* d_in, const int* in_sizes, int n_in,
                              void* d_out, int out_size, void* d_ws, size_t ws_size,
                              hipStream_t stream) {
    const float* in = (const float*)d_in[0];
    float* out = (float*)d_out;

    // workspace: sigmoid (2MB) | tidx (1030*16B) | twgt (1030*16B)
    float* sig   = (float*)d_ws;
    int4*  tidx  = (int4*)(sig + B_ * HI * WI);
    float4* twgt = (float4*)((int*)tidx + 4 * NEXT);

    k_taps<<<dim3((NEXT + 255) / 256), dim3(256), 0, stream>>>(tidx, twgt);

    int n4 = B_ * HI * WI / 4;
    k_sigmoid<<<dim3(n4 / 256), dim3(256), 0, stream>>>((const float4*)in, (float4*)sig, n4);

    dim3 g(WO / T, HO / T, B_);  // (16, 16, 8)
    k_fused<<<g, dim3(64, 4), 0, stream>>>(sig, tidx, twgt, out);
}

// Round 5
// 41.134 us; speedup vs baseline: 4.6934x; 1.9413x over previous
//
#include <hip/hip_runtime.h>

#define B_ 8
#define HI 256
#define WI 256
#define HO 1024
#define WO 1024

#define TLE 64            // output tile (64x64), grid 16x16x8
#define FRY 70            // frame rows: halo 3 top / 3 bottom
#define VW  18            // float4 per frame row (72 floats: halo 4 left / 4 right)
#define NV  (FRY * VW)    // 1260 vec4s per buffer
#define NTAP 1032         // extended tap table: entry j <-> coord g = j-4
#define EXPM5 0.0067379470f
#define GW0 0.27406862f
#define GW1 0.45186276f

// ---------- combined sigmoid (blocks 0..511) + tap tables (blocks 512..516) ----------
__global__ void k_pre(const float4* __restrict__ in, float4* __restrict__ sig,
                      int4* __restrict__ tidx, float4* __restrict__ twgt) {
    int blk = blockIdx.x, t = threadIdx.x;
    if (blk < 512) {
        int i = blk * 256 + t;
        float4 v = in[i];
        v.x = 1.0f / (1.0f + __expf(-v.x));
        v.y = 1.0f / (1.0f + __expf(-v.y));
        v.z = 1.0f / (1.0f + __expf(-v.z));
        v.w = 1.0f / (1.0f + __expf(-v.w));
        sig[i] = v;
    } else {
        int j = (blk - 512) * 256 + t;
        if (j < NTAP) {
            int gc = min(max(j - 4, 0), HO - 1);
            const float a = -0.75f;
            float src = (float)gc * ((float)(HI - 1) / (float)(HO - 1));
            float fi0 = floorf(src);
            float tt = src - fi0;
            float t1 = tt + 1.0f;
            float w0 = ((a * t1 - 5.0f * a) * t1 + 8.0f * a) * t1 - 4.0f * a;
            float w1 = ((a + 2.0f) * tt - (a + 3.0f)) * tt * tt + 1.0f;
            float u = 1.0f - tt;
            float w2 = ((a + 2.0f) * u - (a + 3.0f)) * u * u + 1.0f;
            float u2 = 2.0f - tt;
            float w3 = ((a * u2 - 5.0f * a) * u2 + 8.0f * a) * u2 - 4.0f * a;
            int i0 = (int)fi0;
            int4 id;
            id.x = min(max(i0 - 1, 0), HI - 1);
            id.y = min(max(i0,     0), HI - 1);
            id.z = min(max(i0 + 1, 0), HI - 1);
            id.w = min(max(i0 + 2, 0), HI - 1);
            tidx[j] = id;
            twgt[j] = make_float4(w0, w1, w2, w3);
        }
    }
}

// ---------- post-resize pipeline, EDGE=false is branch/check-free ----------
template<bool EDGE>
__device__ __forceinline__ void stages(float4* __restrict__ A, float4* __restrict__ Bq,
                                       const int4* __restrict__ tidx,
                                       const float4* __restrict__ twgt,
                                       float* __restrict__ out,
                                       int bx, int by, int b, int tid, int ty, int tx, int rlo) {
    // ---- 1b: vertical bicubic: hres(Bq) -> A ----
    if (tid < 252) {
        for (int y = ty; y < FRY; y += 14) {
            int jy = by * TLE + y + 1;
            int4 iy = tidx[jy];
            float4 wy = twgt[jy];
            float4 h0 = Bq[(iy.x - rlo) * VW + tx];
            float4 h1 = Bq[(iy.y - rlo) * VW + tx];
            float4 h2 = Bq[(iy.z - rlo) * VW + tx];
            float4 h3 = Bq[(iy.w - rlo) * VW + tx];
            float4 v;
            v.x = wy.x * h0.x + wy.y * h1.x + wy.z * h2.x + wy.w * h3.x;
            v.y = wy.x * h0.y + wy.y * h1.y + wy.z * h2.y + wy.w * h3.y;
            v.z = wy.x * h0.z + wy.y * h1.z + wy.z * h2.z + wy.w * h3.z;
            v.w = wy.x * h0.w + wy.y * h1.w + wy.z * h2.w + wy.w * h3.w;
            if (EDGE) {
                int gy = by * TLE + y - 3;
                int gxb = bx * TLE + (tx << 2) - 4;
                if ((unsigned)gy >= HO) { v.x = v.y = v.z = v.w = 0.0f; }
                else {
                    if ((unsigned)(gxb + 0) >= WO) v.x = 0.0f;
                    if ((unsigned)(gxb + 1) >= WO) v.y = 0.0f;
                    if ((unsigned)(gxb + 2) >= WO) v.z = 0.0f;
                    if ((unsigned)(gxb + 3) >= WO) v.w = 0.0f;
                }
            }
            A[y * VW + tx] = v;
        }
    }
    __syncthreads();

    // ---- 2a: horizontal gaussian: A -> Bq ----
    for (int v = tid; v < NV; v += 256) {
        float4 c = A[v], l = A[v - 1], n = A[v + 1];
        float4 r;
        r.x = GW0 * (l.w + c.y) + GW1 * c.x;
        r.y = GW0 * (c.x + c.z) + GW1 * c.y;
        r.z = GW0 * (c.y + c.w) + GW1 * c.z;
        r.w = GW0 * (c.z + n.x) + GW1 * c.w;
        Bq[v] = r;
    }
    __syncthreads();

    // ---- 2b+3a: vertical gaussian + E1 = exp(5*smooth-5): Bq -> A ----
    for (int v = VW + tid; v < NV - VW; v += 256) {
        float4 u = Bq[v - VW], c = Bq[v], d = Bq[v + VW];
        float4 e;
        e.x = __expf(fmaf(5.0f, GW0 * (u.x + d.x) + GW1 * c.x, -5.0f));
        e.y = __expf(fmaf(5.0f, GW0 * (u.y + d.y) + GW1 * c.y, -5.0f));
        e.z = __expf(fmaf(5.0f, GW0 * (u.z + d.z) + GW1 * c.z, -5.0f));
        e.w = __expf(fmaf(5.0f, GW0 * (u.w + d.w) + GW1 * c.w, -5.0f));
        if (EDGE) {
            int y = v / VW, x4 = v - y * VW;
            int gy = by * TLE + y - 3;
            int gxb = bx * TLE + (x4 << 2) - 4;
            if ((unsigned)gy >= HO) { e.x = e.y = e.z = e.w = EXPM5; }
            else {
                if ((unsigned)(gxb + 0) >= WO) e.x = EXPM5;
                if ((unsigned)(gxb + 1) >= WO) e.y = EXPM5;
                if ((unsigned)(gxb + 2) >= WO) e.z = EXPM5;
                if ((unsigned)(gxb + 3) >= WO) e.w = EXPM5;
            }
        }
        A[v] = e;
    }
    __syncthreads();

    // ---- 3b: row sums of E1: A -> Bq ----
    for (int v = VW + tid; v < NV - VW; v += 256) {
        float4 c = A[v], l = A[v - 1], n = A[v + 1];
        float4 r;
        r.x = l.w + c.x + c.y;
        r.y = c.x + c.y + c.z;
        r.z = c.y + c.z + c.w;
        r.w = c.z + c.w + n.x;
        Bq[v] = r;
    }
    __syncthreads();

    // ---- 3c+4a: E2 = min(col-sum, 1): Bq -> A ----
    // (dilate#1: exp(5*clip(1+ln(S)/5,0,1)-5) == min(S,1); lower clip never fires)
    for (int v = 2 * VW + tid; v < NV - 2 * VW; v += 256) {
        float4 u = Bq[v - VW], c = Bq[v], d = Bq[v + VW];
        float4 e;
        e.x = fminf(u.x + c.x + d.x, 1.0f);
        e.y = fminf(u.y + c.y + d.y, 1.0f);
        e.z = fminf(u.z + c.z + d.z, 1.0f);
        e.w = fminf(u.w + c.w + d.w, 1.0f);
        if (EDGE) {
            int y = v / VW, x4 = v - y * VW;
            int gy = by * TLE + y - 3;
            int gxb = bx * TLE + (x4 << 2) - 4;
            if ((unsigned)gy >= HO) { e.x = e.y = e.z = e.w = EXPM5; }
            else {
                if ((unsigned)(gxb + 0) >= WO) e.x = EXPM5;
                if ((unsigned)(gxb + 1) >= WO) e.y = EXPM5;
                if ((unsigned)(gxb + 2) >= WO) e.z = EXPM5;
                if ((unsigned)(gxb + 3) >= WO) e.w = EXPM5;
            }
        }
        A[v] = e;
    }
    __syncthreads();

    // ---- 4b: row sums of E2: A -> Bq ----
    for (int v = 2 * VW + tid; v < NV - 2 * VW; v += 256) {
        float4 c = A[v], l = A[v - 1], n = A[v + 1];
        float4 r;
        r.x = l.w + c.x + c.y;
        r.y = c.x + c.y + c.z;
        r.z = c.y + c.z + c.w;
        r.w = c.z + c.w + n.x;
        Bq[v] = r;
    }
    __syncthreads();

    // ---- 4c: out = clamp(1 + 0.2*ln(col-sum), 0, 1), vec4 stores ----
    {
        const int r0 = tid >> 4;
        const int xq = tid & 15;
        const int xv = xq + 1;
        for (int k = 0; k < 4; ++k) {
            int y = r0 + (k << 4) + 3;
            int v = y * VW + xv;
            float4 u = Bq[v - VW], c = Bq[v], d = Bq[v + VW];
            float4 o;
            float s;
            s = u.x + c.x + d.x; o.x = fmaxf(fminf(fmaf(0.2f, __logf(s), 1.0f), 1.0f), 0.0f);
            s = u.y + c.y + d.y; o.y = fmaxf(fminf(fmaf(0.2f, __logf(s), 1.0f), 1.0f), 0.0f);
            s = u.z + c.z + d.z; o.z = fmaxf(fminf(fmaf(0.2f, __logf(s), 1.0f), 1.0f), 0.0f);
            s = u.w + c.w + d.w; o.w = fmaxf(fminf(fmaf(0.2f, __logf(s), 1.0f), 1.0f), 0.0f);
            size_t off = ((size_t)(b * HO + by * TLE + r0 + (k << 4)) * WO) + bx * TLE + (xq << 2);
            *reinterpret_cast<float4*>(out + off) = o;
        }
    }
}

__global__ __launch_bounds__(256, 4) void k_fused(const float* __restrict__ sig,
                                                  const int4* __restrict__ tidx,
                                                  const float4* __restrict__ twgt,
                                                  float* __restrict__ out) {
    __shared__ float4 Abuf[NV + 2];
    __shared__ float4 Bbuf[NV + 2];
    float4* A  = Abuf + 1;   // A[-1] / A[NV] are safe in-bounds pads
    float4* Bq = Bbuf + 1;

    const int tid = threadIdx.x;
    const int bx = blockIdx.x, by = blockIdx.y, b = blockIdx.z;
    const int ty = tid / VW;            // [0,14) for tid < 252
    const int tx = tid - ty * VW;
    const float* p = sig + b * (HI * WI);

    const int jy0 = by * TLE + 1;
    const int rlo = tidx[jy0].x;
    const int rhi = tidx[jy0 + FRY - 1].w;
    const int nrows = rhi - rlo + 1;    // <= 22

    // ---- 1a: horizontal bicubic on needed input rows -> Bq (hres) ----
    if (tid < 252) {
        int jx = bx * TLE + (tx << 2);
        int4   i0 = tidx[jx],     i1 = tidx[jx + 1], i2 = tidx[jx + 2], i3 = tidx[jx + 3];
        float4 w0 = twgt[jx],     w1 = twgt[jx + 1], w2 = twgt[jx + 2], w3 = twgt[jx + 3];
        for (int y = ty; y < nrows; y += 14) {
            const float* row = p + (rlo + y) * WI;
            float4 hv;
            hv.x = w0.x * row[i0.x] + w0.y * row[i0.y] + w0.z * row[i0.z] + w0.w * row[i0.w];
            hv.y = w1.x * row[i1.x] + w1.y * row[i1.y] + w1.z * row[i1.z] + w1.w * row[i1.w];
            hv.z = w2.x * row[i2.x] + w2.y * row[i2.y] + w2.z * row[i2.z] + w2.w * row[i2.w];
            hv.w = w3.x * row[i3.x] + w3.y * row[i3.y] + w3.z * row[i3.z] + w3.w * row[i3.w];
            Bq[y * VW + tx] = hv;
        }
    }
    __syncthreads();

    const bool edge = (bx == 0) | (bx == 15) | (by == 0) | (by == 15);
    if (edge) stages<true >(A, Bq, tidx, twgt, out, bx, by, b, tid, ty, tx, rlo);
    else      stages<false>(A, Bq, tidx, twgt, out, bx, by, b, tid, ty, tx, rlo);
}

extern "C" void kernel_launch(void* const* d_in, const int* in_sizes, int n_in,
                              void* d_out, int out_size, void* d_ws, size_t ws_size,
                              hipStream_t stream) {
    const float* in = (const float*)d_in[0];
    float* out = (float*)d_out;

    // workspace: sigmoid (2MB) | tidx (1032*16B) | twgt (1032*16B)
    float*  sig  = (float*)d_ws;
    int4*   tidx = (int4*)(sig + B_ * HI * WI);
    float4* twgt = (float4*)((int*)tidx + 4 * NTAP);

    k_pre<<<dim3(512 + (NTAP + 255) / 256), dim3(256), 0, stream>>>(
        (const float4*)in, (float4*)sig, tidx, twgt);

    dim3 g(WO / TLE, HO / TLE, B_);  // (16,16,8)
    k_fused<<<g, dim3(256), 0, stream>>>(sig, tidx, twgt, out);
}

// Round 7
// 40.145 us; speedup vs baseline: 4.8090x; 1.0246x over previous
//
#include <hip/hip_runtime.h>

#define B_ 8
#define HI 256
#define WI 256
#define HO 1024
#define WO 1024

#define TLE 64            // output tile 64x64, grid 16x16x8
#define FRY 70            // frame rows (halo 3 top/bottom)
#define VW  18            // float4 per frame row (72 floats: halo 4 left/right)
#define NV  (FRY * VW)
#define NTAP 1032         // table entry j <-> coord g = j-4
#define HRMAX 26          // max low-res rows a tile needs (measured bound 24)
#define EXPM5 0.0067379470f
#define GW0 0.27406862f
#define GW1 0.45186276f

// ---------- sigmoid (blocks 0..511) + combined smooth*resize 6-tap tables ----------
// Combined filter: conv(gauss3, keys-cubic4) on the low-res grid; per output coord
// g: base row + 6 weights. Boundary: gauss terms with y+d outside [0,1023] dropped
// (high-res zero-pad); cubic tap indices clamped to [0,255] (reference clamp).
__global__ void k_pre(const float4* __restrict__ in, float4* __restrict__ sig,
                      float4* __restrict__ wA, float4* __restrict__ wB, int* __restrict__ vb) {
    int blk = blockIdx.x, t = threadIdx.x;
    if (blk < 512) {
        int i = blk * 256 + t;
        float4 v = in[i];
        v.x = 1.0f / (1.0f + __expf(-v.x));
        v.y = 1.0f / (1.0f + __expf(-v.y));
        v.z = 1.0f / (1.0f + __expf(-v.z));
        v.w = 1.0f / (1.0f + __expf(-v.w));
        sig[i] = v;
        return;
    }
    int j = (blk - 512) * 256 + t;
    if (j >= NTAP) return;
    int yc = min(max(j - 4, 0), HO - 1);
    const float sc = 255.0f / 1023.0f;
    int base = (int)floorf((float)yc * sc) - 2;
    float w8[6] = {0.f, 0.f, 0.f, 0.f, 0.f, 0.f};
    const float g1[3] = {GW0, GW1, GW0};
    for (int d = -1; d <= 1; ++d) {
        int yd = yc + d;
        if (yd < 0 || yd >= HO) continue;
        float src = (float)yd * sc;
        float fi0 = floorf(src);
        float tt = src - fi0;
        const float a = -0.75f;
        float t1 = tt + 1.0f;
        float c0 = ((a * t1 - 5.0f * a) * t1 + 8.0f * a) * t1 - 4.0f * a;
        float c1 = ((a + 2.0f) * tt - (a + 3.0f)) * tt * tt + 1.0f;
        float u = 1.0f - tt;
        float c2 = ((a + 2.0f) * u - (a + 3.0f)) * u * u + 1.0f;
        float u2 = 2.0f - tt;
        float c3 = ((a * u2 - 5.0f * a) * u2 + 8.0f * a) * u2 - 4.0f * a;
        int s0 = ((int)fi0 - 1) - base;   // in [0,2]
        float gg = g1[d + 1];
        w8[s0 + 0] += gg * c0;
        w8[s0 + 1] += gg * c1;
        w8[s0 + 2] += gg * c2;
        w8[s0 + 3] += gg * c3;
    }
    vb[j] = base;
    wA[j] = make_float4(w8[0], w8[1], w8[2], w8[3]);
    wB[j] = make_float4(w8[4], w8[5], 0.0f, 0.0f);
}

__device__ __forceinline__ float4 rsum(const float4* __restrict__ buf, int v) {
    float4 l = buf[v - 1], c = buf[v], n = buf[v + 1];
    float4 r;
    r.x = l.w + c.x + c.y;
    r.y = c.x + c.y + c.z;
    r.z = c.y + c.z + c.w;
    r.w = c.z + c.w + n.x;
    return r;
}

template<bool EDGE>
__device__ __forceinline__ void stages(float4* __restrict__ A, float4* __restrict__ Bq,
                                       const float* __restrict__ p,
                                       const float4* __restrict__ wA,
                                       const float4* __restrict__ wB,
                                       const int* __restrict__ vb,
                                       float* __restrict__ out,
                                       int bx, int by, int b, int tid, int tx, int ty, int rlo, int nrows) {
    // ---- Stage A: horizontal 6-tap (smooth*resize) on low-res rows -> Bq[nrows][18] ----
    if (tid < 252) {
        float wgt[4][6];
        int   rix[4][6];
        int jx = bx * TLE + (tx << 2);
#pragma unroll
        for (int k = 0; k < 4; ++k) {
            int j = jx + k;
            float4 wa = wA[j], wb = wB[j];
            int bh = vb[j];
            wgt[k][0] = wa.x; wgt[k][1] = wa.y; wgt[k][2] = wa.z; wgt[k][3] = wa.w;
            wgt[k][4] = wb.x; wgt[k][5] = wb.y;
#pragma unroll
            for (int s = 0; s < 6; ++s) rix[k][s] = min(max(bh + s, 0), HI - 1);
        }
        for (int r = ty; r < nrows; r += 14) {
            const float* row = p + (rlo + r) * WI;
            float hv[4];
#pragma unroll
            for (int k = 0; k < 4; ++k) {
                float s = 0.0f;
#pragma unroll
                for (int s6 = 0; s6 < 6; ++s6) s += wgt[k][s6] * row[rix[k][s6]];
                hv[k] = s;
            }
            Bq[r * VW + tx] = make_float4(hv[0], hv[1], hv[2], hv[3]);
        }
    }
    __syncthreads();

    // ---- Stage B: vertical 6-tap + E1 = exp(5*S-5) -> A[70][18] ----
    if (tid < 252) {
        for (int fy = ty; fy < FRY; fy += 14) {
            int j = by * TLE + fy + 1;
            int bv = vb[j];
            float4 wa = wA[j], wb = wB[j];
            int r0 = min(max(bv + 0, 0), HI - 1) - rlo;
            int r1 = min(max(bv + 1, 0), HI - 1) - rlo;
            int r2 = min(max(bv + 2, 0), HI - 1) - rlo;
            int r3 = min(max(bv + 3, 0), HI - 1) - rlo;
            int r4 = min(max(bv + 4, 0), HI - 1) - rlo;
            int r5 = min(max(bv + 5, 0), HI - 1) - rlo;
            float4 h0 = Bq[r0 * VW + tx], h1 = Bq[r1 * VW + tx], h2 = Bq[r2 * VW + tx];
            float4 h3 = Bq[r3 * VW + tx], h4 = Bq[r4 * VW + tx], h5 = Bq[r5 * VW + tx];
            float4 e;
            e.x = __expf(fmaf(5.0f, wa.x*h0.x + wa.y*h1.x + wa.z*h2.x + wa.w*h3.x + wb.x*h4.x + wb.y*h5.x, -5.0f));
            e.y = __expf(fmaf(5.0f, wa.x*h0.y + wa.y*h1.y + wa.z*h2.y + wa.w*h3.y + wb.x*h4.y + wb.y*h5.y, -5.0f));
            e.z = __expf(fmaf(5.0f, wa.x*h0.z + wa.y*h1.z + wa.z*h2.z + wa.w*h3.z + wb.x*h4.z + wb.y*h5.z, -5.0f));
            e.w = __expf(fmaf(5.0f, wa.x*h0.w + wa.y*h1.w + wa.z*h2.w + wa.w*h3.w + wb.x*h4.w + wb.y*h5.w, -5.0f));
            if (EDGE) {
                int gy = by * TLE + fy - 3;
                int gxb = bx * TLE + (tx << 2) - 4;
                if ((unsigned)gy >= HO) { e.x = e.y = e.z = e.w = EXPM5; }
                else {
                    if ((unsigned)(gxb + 0) >= WO) e.x = EXPM5;
                    if ((unsigned)(gxb + 1) >= WO) e.y = EXPM5;
                    if ((unsigned)(gxb + 2) >= WO) e.z = EXPM5;
                    if ((unsigned)(gxb + 3) >= WO) e.w = EXPM5;
                }
            }
            A[fy * VW + tx] = e;
        }
    }
    __syncthreads();

    // ---- Stage C: E2 = min(3x3 boxsum E1, 1) -> Bq, rows [2,68), rolling col-sum ----
    if (tid < 252) {
        int ys = 2 + ty * 5;
        int ye = min(ys + 5, 68);
        float4 rp = rsum(A, (ys - 1) * VW + tx);
        float4 rc = rsum(A, ys * VW + tx);
        for (int y = ys; y < ye; ++y) {
            float4 rn = rsum(A, (y + 1) * VW + tx);
            float4 e;
            e.x = fminf(rp.x + rc.x + rn.x, 1.0f);
            e.y = fminf(rp.y + rc.y + rn.y, 1.0f);
            e.z = fminf(rp.z + rc.z + rn.z, 1.0f);
            e.w = fminf(rp.w + rc.w + rn.w, 1.0f);
            if (EDGE) {
                int gy = by * TLE + y - 3;
                int gxb = bx * TLE + (tx << 2) - 4;
                if ((unsigned)gy >= HO) { e.x = e.y = e.z = e.w = EXPM5; }
                else {
                    if ((unsigned)(gxb + 0) >= WO) e.x = EXPM5;
                    if ((unsigned)(gxb + 1) >= WO) e.y = EXPM5;
                    if ((unsigned)(gxb + 2) >= WO) e.z = EXPM5;
                    if ((unsigned)(gxb + 3) >= WO) e.w = EXPM5;
                }
            }
            Bq[y * VW + tx] = e;
            rp = rc; rc = rn;
        }
    }
    __syncthreads();

    // ---- Stage D: out = clamp(1 + 0.2*ln(3x3 boxsum E2), 0, 1), rolling, vec4 stores ----
    {
        int dx = tid & 15;
        int dty = tid >> 4;
        int vc = 1 + dx;
        int ys = 3 + dty * 4;
        float4 rp = rsum(Bq, (ys - 1) * VW + vc);
        float4 rc = rsum(Bq, ys * VW + vc);
        size_t obase = ((size_t)(b * HO + by * TLE + ys - 3) * WO) + bx * TLE + (dx << 2);
#pragma unroll
        for (int k = 0; k < 4; ++k) {
            float4 rn = rsum(Bq, (ys + k + 1) * VW + vc);
            float4 o; float s;
            s = rp.x + rc.x + rn.x; o.x = fmaxf(fminf(fmaf(0.2f, __logf(s), 1.0f), 1.0f), 0.0f);
            s = rp.y + rc.y + rn.y; o.y = fmaxf(fminf(fmaf(0.2f, __logf(s), 1.0f), 1.0f), 0.0f);
            s = rp.z + rc.z + rn.z; o.z = fmaxf(fminf(fmaf(0.2f, __logf(s), 1.0f), 1.0f), 0.0f);
            s = rp.w + rc.w + rn.w; o.w = fmaxf(fminf(fmaf(0.2f, __logf(s), 1.0f), 1.0f), 0.0f);
            *reinterpret_cast<float4*>(out + obase) = o;
            obase += WO;
            rp = rc; rc = rn;
        }
    }
}

__global__ __launch_bounds__(256, 3) void k_fused(const float* __restrict__ sig,
                                                  const float4* __restrict__ wA,
                                                  const float4* __restrict__ wB,
                                                  const int* __restrict__ vb,
                                                  float* __restrict__ out) {
    __shared__ float4 Abuf[NV + 2];
    __shared__ float4 Bbuf[NV + 2];
    float4* A  = Abuf + 1;
    float4* Bq = Bbuf + 1;

    const int tid = threadIdx.x;
    const int bx = blockIdx.x, by = blockIdx.y, b = blockIdx.z;
    const int ty = tid / VW;    // [0,14) for tid < 252
    const int tx = tid - ty * VW;
    const float* p = sig + b * (HI * WI);

    const int rlo = max(vb[by * TLE + 1], 0);
    const int rhi = min(vb[by * TLE + FRY] + 5, HI - 1);
    const int nrows = rhi - rlo + 1;   // <= HRMAX

    const bool edge = (bx == 0) | (bx == 15) | (by == 0) | (by == 15);
    if (edge) stages<true >(A, Bq, p, wA, wB, vb, out, bx, by, b, tid, tx, ty, rlo, nrows);
    else      stages<false>(A, Bq, p, wA, wB, vb, out, bx, by, b, tid, tx, ty, rlo, nrows);
}

extern "C" void kernel_launch(void* const* d_in, const int* in_sizes, int n_in,
                              void* d_out, int out_size, void* d_ws, size_t ws_size,
                              hipStream_t stream) {
    const float* in = (const float*)d_in[0];
    float* out = (float*)d_out;

    // workspace: sigmoid (2MB) | wA (16.5KB) | wB (16.5KB) | vb (4.1KB)
    float*  sig = (float*)d_ws;
    float4* wA  = (float4*)(sig + B_ * HI * WI);
    float4* wB  = wA + NTAP;
    int*    vb  = (int*)(wB + NTAP);

    k_pre<<<dim3(512 + (NTAP + 255) / 256), dim3(256), 0, stream>>>(
        (const float4*)in, (float4*)sig, wA, wB, vb);

    dim3 g(WO / TLE, HO / TLE, B_);  // (16,16,8)
    k_fused<<<g, dim3(256), 0, stream>>>(sig, wA, wB, vb, out);
}

// Round 9
// 33.824 us; speedup vs baseline: 5.7077x; 1.1869x over previous
//
#include <hip/hip_runtime.h>

#define B_ 8
#define HI 256
#define WI 256
#define HO 1024
#define WO 1024

#define TLE 64            // output tile 64x64, grid 16x16x8
#define FRY 70            // frame rows (halo 3 top/bottom)
#define VW  18            // float4 per frame row (72 floats: halo 4 left/right)
#define NV  (FRY * VW)
#define NR  24            // staged low-res rows (worst-case span 18+6)
#define NC  24            // staged low-res cols
#define SSTR 25           // slice row stride in floats (odd -> bank spread)
#define EXPM5 0.0067379470f
#define GW0 0.27406862f
#define GW1 0.45186276f
#define SC  (255.0f / 1023.0f)
#define F5L2E 7.2134752f  // 5*log2(e)

// Combined conv(gauss3, keys-cubic4) 6-tap for one coordinate. g may be out of
// [0,1024): clamped (result then overridden by EDGE logic downstream). Gauss
// terms with neighbor outside [0,1024) dropped (high-res zero-pad); cubic tap
// indices are clamped by the caller (reference's jnp.clip).
__device__ __forceinline__ void tap6(int g, int* base_out, float w[6]) {
    int yc = min(max(g, 0), HO - 1);
    int base = (int)floorf((float)yc * SC) - 2;
#pragma unroll
    for (int s = 0; s < 6; ++s) w[s] = 0.0f;
#pragma unroll
    for (int d = -1; d <= 1; ++d) {
        int yd = yc + d;
        if (yd < 0 || yd >= HO) continue;
        float src = (float)yd * SC;
        float fi0 = floorf(src);
        float tt = src - fi0;
        const float a = -0.75f;
        float t1 = tt + 1.0f;
        float c0 = ((a * t1 - 5.0f * a) * t1 + 8.0f * a) * t1 - 4.0f * a;
        float c1 = ((a + 2.0f) * tt - (a + 3.0f)) * tt * tt + 1.0f;
        float u = 1.0f - tt;
        float c2 = ((a + 2.0f) * u - (a + 3.0f)) * u * u + 1.0f;
        float u2 = 2.0f - tt;
        float c3 = ((a * u2 - 5.0f * a) * u2 + 8.0f * a) * u2 - 4.0f * a;
        int s0 = ((int)fi0 - 1) - base;   // in [0,2]
        float gg = (d == 0) ? GW1 : GW0;
        w[s0 + 0] += gg * c0;
        w[s0 + 1] += gg * c1;
        w[s0 + 2] += gg * c2;
        w[s0 + 3] += gg * c3;
    }
    *base_out = base;
}

__device__ __forceinline__ float4 rsum(const float4* __restrict__ buf, int v) {
    float4 l = buf[v - 1], c = buf[v], n = buf[v + 1];
    float4 r;
    r.x = l.w + c.x + c.y;
    r.y = c.x + c.y + c.z;
    r.z = c.y + c.z + c.w;
    r.w = c.z + c.w + n.x;
    return r;
}

template<bool EDGE>
__device__ __forceinline__ void stages(float4* __restrict__ A, float4* __restrict__ Bq,
                                       const float* __restrict__ SL,
                                       const float4* __restrict__ xA, const float4* __restrict__ xB,
                                       const float4* __restrict__ vA, const float4* __restrict__ vB,
                                       float* __restrict__ out,
                                       int bx, int by, int b, int tid, int tx, int ty,
                                       int rlo, int clo) {
    // ---- Stage A: horizontal 6-tap from LDS slice -> hres in A rows [0,NR) ----
    if (tid < 252) {
        float xw[4][6];
        int lcb[4];
        int lce[4][6];
        int xe0 = tx << 2;
#pragma unroll
        for (int k = 0; k < 4; ++k) {
            float4 a = xA[xe0 + k], bv4 = xB[xe0 + k];
            xw[k][0] = a.x; xw[k][1] = a.y; xw[k][2] = a.z; xw[k][3] = a.w;
            xw[k][4] = bv4.x; xw[k][5] = bv4.y;
            int bh = __float_as_int(bv4.z);
            if (EDGE) {
#pragma unroll
                for (int s = 0; s < 6; ++s) lce[k][s] = min(max(bh + s, 0), HI - 1) - clo;
            } else {
                lcb[k] = bh - clo;
            }
        }
        for (int r = ty; r < NR; r += 14) {
            const float* srow = SL + r * SSTR;
            float hv[4];
#pragma unroll
            for (int k = 0; k < 4; ++k) {
                float s = 0.0f;
                if (EDGE) {
#pragma unroll
                    for (int s6 = 0; s6 < 6; ++s6) s += xw[k][s6] * srow[lce[k][s6]];
                } else {
                    const float* q = srow + lcb[k];
#pragma unroll
                    for (int s6 = 0; s6 < 6; ++s6) s += xw[k][s6] * q[s6];
                }
                hv[k] = s;
            }
            A[r * VW + tx] = make_float4(hv[0], hv[1], hv[2], hv[3]);
        }
    }
    __syncthreads();

    // ---- Stage B: vertical 6-tap + E1 = exp2(fma-chain - 5*log2e) -> Bq [0,70) ----
    if (tid < 252) {
        for (int fy = ty; fy < FRY; fy += 14) {
            float4 wa = vA[fy], wb = vB[fy];
            int bv = __float_as_int(wb.z);
            float4 h0, h1, h2, h3, h4, h5;
            if (!EDGE) {
                const float4* h = &A[(bv - rlo) * VW + tx];
                h0 = h[0]; h1 = h[VW]; h2 = h[2 * VW]; h3 = h[3 * VW]; h4 = h[4 * VW]; h5 = h[5 * VW];
            } else {
                int r0 = min(max(bv + 0, 0), HI - 1) - rlo;
                int r1 = min(max(bv + 1, 0), HI - 1) - rlo;
                int r2 = min(max(bv + 2, 0), HI - 1) - rlo;
                int r3 = min(max(bv + 3, 0), HI - 1) - rlo;
                int r4 = min(max(bv + 4, 0), HI - 1) - rlo;
                int r5 = min(max(bv + 5, 0), HI - 1) - rlo;
                h0 = A[r0 * VW + tx]; h1 = A[r1 * VW + tx]; h2 = A[r2 * VW + tx];
                h3 = A[r3 * VW + tx]; h4 = A[r4 * VW + tx]; h5 = A[r5 * VW + tx];
            }
            float4 e;
            e.x = exp2f(fmaf(wa.x, h0.x, fmaf(wa.y, h1.x, fmaf(wa.z, h2.x, fmaf(wa.w, h3.x, fmaf(wb.x, h4.x, fmaf(wb.y, h5.x, -F5L2E)))))));
            e.y = exp2f(fmaf(wa.x, h0.y, fmaf(wa.y, h1.y, fmaf(wa.z, h2.y, fmaf(wa.w, h3.y, fmaf(wb.x, h4.y, fmaf(wb.y, h5.y, -F5L2E)))))));
            e.z = exp2f(fmaf(wa.x, h0.z, fmaf(wa.y, h1.z, fmaf(wa.z, h2.z, fmaf(wa.w, h3.z, fmaf(wb.x, h4.z, fmaf(wb.y, h5.z, -F5L2E)))))));
            e.w = exp2f(fmaf(wa.x, h0.w, fmaf(wa.y, h1.w, fmaf(wa.z, h2.w, fmaf(wa.w, h3.w, fmaf(wb.x, h4.w, fmaf(wb.y, h5.w, -F5L2E)))))));
            if (EDGE) {
                int gy = by * TLE + fy - 3;
                int gxb = bx * TLE + (tx << 2) - 4;
                if ((unsigned)gy >= HO) { e.x = e.y = e.z = e.w = EXPM5; }
                else {
                    if ((unsigned)(gxb + 0) >= WO) e.x = EXPM5;
                    if ((unsigned)(gxb + 1) >= WO) e.y = EXPM5;
                    if ((unsigned)(gxb + 2) >= WO) e.z = EXPM5;
                    if ((unsigned)(gxb + 3) >= WO) e.w = EXPM5;
                }
            }
            Bq[fy * VW + tx] = e;
        }
    }
    __syncthreads();

    // ---- Stage C: E2 = min(3x3 boxsum E1, 1): Bq -> A rows [2,68), rolling ----
    if (tid < 252) {
        int ys = 2 + ty * 5;
        int ye = min(ys + 5, 68);
        float4 rp = rsum(Bq, (ys - 1) * VW + tx);
        float4 rc = rsum(Bq, ys * VW + tx);
        for (int y = ys; y < ye; ++y) {
            float4 rn = rsum(Bq, (y + 1) * VW + tx);
            float4 e;
            e.x = fminf(rp.x + rc.x + rn.x, 1.0f);
            e.y = fminf(rp.y + rc.y + rn.y, 1.0f);
            e.z = fminf(rp.z + rc.z + rn.z, 1.0f);
            e.w = fminf(rp.w + rc.w + rn.w, 1.0f);
            if (EDGE) {
                int gy = by * TLE + y - 3;
                int gxb = bx * TLE + (tx << 2) - 4;
                if ((unsigned)gy >= HO) { e.x = e.y = e.z = e.w = EXPM5; }
                else {
                    if ((unsigned)(gxb + 0) >= WO) e.x = EXPM5;
                    if ((unsigned)(gxb + 1) >= WO) e.y = EXPM5;
                    if ((unsigned)(gxb + 2) >= WO) e.z = EXPM5;
                    if ((unsigned)(gxb + 3) >= WO) e.w = EXPM5;
                }
            }
            A[y * VW + tx] = e;
            rp = rc; rc = rn;
        }
    }
    __syncthreads();

    // ---- Stage D: out = clamp(1 + 0.2*ln(3x3 boxsum E2), 0, 1), vec4 stores ----
    {
        int dx = tid & 15;
        int dty = tid >> 4;
        int vc = 1 + dx;
        int ys = 3 + dty * 4;
        float4 rp = rsum(A, (ys - 1) * VW + vc);
        float4 rc = rsum(A, ys * VW + vc);
        size_t obase = ((size_t)(b * HO + by * TLE + ys - 3) * WO) + bx * TLE + (dx << 2);
#pragma unroll
        for (int k = 0; k < 4; ++k) {
            float4 rn = rsum(A, (ys + k + 1) * VW + vc);
            float4 o; float s;
            s = rp.x + rc.x + rn.x; o.x = fmaxf(fminf(fmaf(0.13862944f, __log2f(s), 1.0f), 1.0f), 0.0f);
            s = rp.y + rc.y + rn.y; o.y = fmaxf(fminf(fmaf(0.13862944f, __log2f(s), 1.0f), 1.0f), 0.0f);
            s = rp.z + rc.z + rn.z; o.z = fmaxf(fminf(fmaf(0.13862944f, __log2f(s), 1.0f), 1.0f), 0.0f);
            s = rp.w + rc.w + rn.w; o.w = fmaxf(fminf(fmaf(0.13862944f, __log2f(s), 1.0f), 1.0f), 0.0f);
            *reinterpret_cast<float4*>(out + obase) = o;
            obase += WO;
            rp = rc; rc = rn;
        }
    }
}

__global__ __launch_bounds__(256, 3) void k_fused(const float* __restrict__ in,
                                                  float* __restrict__ out) {
    __shared__ float4 Abuf[NV + 2];
    __shared__ float4 Bbuf[NV + 2];
    __shared__ float4 xAs[72], xBs[72], vAs[FRY], vBs[FRY];
    float4* A  = Abuf + 1;
    float4* Bq = Bbuf + 1;
    float*  SL = (float*)Bq;   // slice alias: dead before Bq's first write (stage B)

    const int tid = threadIdx.x;
    const int bx = blockIdx.x, by = blockIdx.y, b = blockIdx.z;
    const int ty = tid / VW;
    const int tx = tid - ty * VW;

    const int rlo = max((int)floorf((float)min(max(by * TLE - 3, 0), HO - 1) * SC) - 2, 0);
    const int clo = max((int)floorf((float)min(max(bx * TLE - 4, 0), HO - 1) * SC) - 2, 0);

    // ---- Phase 0: tables into LDS + sigmoid'd input slice into LDS ----
    if (tid < FRY) {
        int base; float w[6];
        tap6(by * TLE + tid - 3, &base, w);
        vAs[tid] = make_float4(w[0] * F5L2E, w[1] * F5L2E, w[2] * F5L2E, w[3] * F5L2E);
        vBs[tid] = make_float4(w[4] * F5L2E, w[5] * F5L2E, __int_as_float(base), 0.0f);
    } else if (tid >= 128 && tid < 200) {
        int xe = tid - 128;
        int base; float w[6];
        tap6(bx * TLE + xe - 4, &base, w);
        xAs[xe] = make_float4(w[0], w[1], w[2], w[3]);
        xBs[xe] = make_float4(w[4], w[5], __int_as_float(base), 0.0f);
    }
    {
        const float* pin = in + b * (HI * WI);
        int cc = tid & 31, rr0 = tid >> 5;
        if (cc < NC) {
            for (int rr = rr0; rr < NR; rr += 8) {
                int row = min(rlo + rr, HI - 1);
                int col = min(clo + cc, HI - 1);
                float x = pin[row * WI + col];
                SL[rr * SSTR + cc] = 1.0f / (1.0f + __expf(-x));
            }
        }
    }
    __syncthreads();

    const bool edge = (bx == 0) | (bx == 15) | (by == 0) | (by == 15);
    if (edge) stages<true >(A, Bq, SL, xAs, xBs, vAs, vBs, out, bx, by, b, tid, tx, ty, rlo, clo);
    else      stages<false>(A, Bq, SL, xAs, xBs, vAs, vBs, out, bx, by, b, tid, tx, ty, rlo, clo);
}

extern "C" void kernel_launch(void* const* d_in, const int* in_sizes, int n_in,
                              void* d_out, int out_size, void* d_ws, size_t ws_size,
                              hipStream_t stream) {
    const float* in = (const float*)d_in[0];
    float* out = (float*)d_out;
    dim3 g(WO / TLE, HO / TLE, B_);   // (16,16,8)
    k_fused<<<g, dim3(256), 0, stream>>>(in, out);
}

// Round 10
// 29.820 us; speedup vs baseline: 6.4741x; 1.1343x over previous
//
#include <hip/hip_runtime.h>

#define B_ 8
#define HI 256
#define WI 256
#define HO 1024
#define WO 1024

#define TLE 64            // output tile 64x64, grid 16x16x8
#define NRS 24            // staged low-res rows/cols
#define SSTR 25           // slice stride (floats)
#define HS 18             // hres row stride (vec4)
#define ES 19             // E1 row stride (vec4, odd -> strip groups hit different banks)
#define SC (255.0f / 1023.0f)
#define F5L2E 7.2134752f  // 5*log2(e)
#define EXPM5 0.0067379470f
#define GW0 0.27406862f
#define GW1 0.45186276f
#define C02 0.13862944f   // 0.2*ln(2)

// Combined conv(gauss3, keys-cubic4) 6-tap. OOB coord (zero-pad region) -> all
// weights 0, so the vertical fma chain yields exp2(-F5L2E) = exp(-5) = pad value.
// Gauss neighbors outside [0,HO) dropped (smooth zero-pad); tap index clamping
// happens at slice staging (= reference's jnp.clip on gather indices).
__device__ __forceinline__ void tap6(int g, int* base_out, float w[6]) {
    int yc = min(max(g, 0), HO - 1);
    int base = (int)floorf((float)yc * SC) - 2;
#pragma unroll
    for (int s = 0; s < 6; ++s) w[s] = 0.0f;
    if (g >= 0 && g < HO) {
#pragma unroll
        for (int d = -1; d <= 1; ++d) {
            int yd = yc + d;
            if (yd < 0 || yd >= HO) continue;
            float src = (float)yd * SC;
            float fi0 = floorf(src);
            float tt = src - fi0;
            const float a = -0.75f;
            float t1 = tt + 1.0f;
            float c0 = ((a * t1 - 5.0f * a) * t1 + 8.0f * a) * t1 - 4.0f * a;
            float c1 = ((a + 2.0f) * tt - (a + 3.0f)) * tt * tt + 1.0f;
            float u = 1.0f - tt;
            float c2 = ((a + 2.0f) * u - (a + 3.0f)) * u * u + 1.0f;
            float u2 = 2.0f - tt;
            float c3 = ((a * u2 - 5.0f * a) * u2 + 8.0f * a) * u2 - 4.0f * a;
            int s0 = ((int)fi0 - 1) - base;   // in [0,2]
            float gg = (d == 0) ? GW1 : GW0;
            w[s0 + 0] += gg * c0;
            w[s0 + 1] += gg * c1;
            w[s0 + 2] += gg * c2;
            w[s0 + 3] += gg * c3;
        }
    }
    *base_out = base;
}

__global__ __launch_bounds__(256, 5) void k_fused(const float* __restrict__ in,
                                                  float* __restrict__ out) {
    __shared__ float4 E1s[68 * ES];                 // 20672 B (aliased by slice in phase 0/A)
    __shared__ float4 Hs[NRS * HS];                 // 6912 B
    __shared__ float4 xAs[72], xBs[72];             // 2304 B
    __shared__ float4 vAs[70], vBs[70];             // 2240 B   -> ~31.4 KB total
    float* SL = (float*)E1s;

    const int tid = threadIdx.x;
    const int bx = blockIdx.x, by = blockIdx.y, b = blockIdx.z;

    const int rlo = (int)floorf((float)min(max(by * TLE - 3, 0), HO - 1) * SC) - 2;
    const int clo = (int)floorf((float)min(max(bx * TLE - 4, 0), HO - 1) * SC) - 2;

    // ---- Phase 0: tables + sigmoid'd clamped input slice ----
    if (tid < 70) {
        int base; float w[6];
        tap6(by * TLE + tid - 3, &base, w);
        vAs[tid] = make_float4(w[0] * F5L2E, w[1] * F5L2E, w[2] * F5L2E, w[3] * F5L2E);
        vBs[tid] = make_float4(w[4] * F5L2E, w[5] * F5L2E, __int_as_float(base), 0.0f);
    } else if (tid >= 128 && tid < 200) {
        int xe = tid - 128;
        int base; float w[6];
        tap6(bx * TLE + xe - 4, &base, w);
        xAs[xe] = make_float4(w[0], w[1], w[2], w[3]);
        xBs[xe] = make_float4(w[4], w[5], __int_as_float(base), 0.0f);
    }
    {
        const float* pin = in + b * (HI * WI);
        int cc = tid & 31, rr0 = tid >> 5;
        if (cc < NRS) {
            for (int rr = rr0; rr < NRS; rr += 8) {
                int row = min(max(rlo + rr, 0), HI - 1);
                int col = min(max(clo + cc, 0), HI - 1);
                float x = pin[row * WI + col];
                SL[rr * SSTR + cc] = 1.0f / (1.0f + __expf(-x));
            }
        }
    }
    __syncthreads();

    const int ty = tid / HS;          // [0,14) for tid < 252
    const int tx = tid - ty * HS;

    // ---- Stage A: horizontal 6-tap -> Hs[24][18] (clamp-free: staging clamped) ----
    if (tid < 252) {
        int xe0 = tx << 2;
        float xw[4][6]; int lcb[4];
#pragma unroll
        for (int k = 0; k < 4; ++k) {
            float4 a4 = xAs[xe0 + k], b4 = xBs[xe0 + k];
            xw[k][0] = a4.x; xw[k][1] = a4.y; xw[k][2] = a4.z; xw[k][3] = a4.w;
            xw[k][4] = b4.x; xw[k][5] = b4.y;
            lcb[k] = __float_as_int(b4.z) - clo;
        }
        for (int r = ty; r < NRS; r += 14) {
            const float* srow = SL + r * SSTR;
            float hv[4];
#pragma unroll
            for (int k = 0; k < 4; ++k) {
                const float* q = srow + lcb[k];
                float s = 0.0f;
#pragma unroll
                for (int j = 0; j < 6; ++j) s += xw[k][j] * q[j];
                hv[k] = s;
            }
            Hs[r * HS + tx] = make_float4(hv[0], hv[1], hv[2], hv[3]);
        }
    }
    __syncthreads();

    // ---- Stage B: vertical 6-tap + E1 = exp2(chain - 5log2e) -> E1s rows fy in [1,69) ----
    if (tid < 252) {
        for (int fy = 1 + ty; fy < 69; fy += 14) {
            float4 wa = vAs[fy], wb = vBs[fy];
            int r0 = __float_as_int(wb.z) - rlo;
            const float4* h = &Hs[r0 * HS + tx];
            float4 h0 = h[0], h1 = h[HS], h2 = h[2 * HS], h3 = h[3 * HS], h4 = h[4 * HS], h5 = h[5 * HS];
            float4 e;
            e.x = exp2f(fmaf(wa.x, h0.x, fmaf(wa.y, h1.x, fmaf(wa.z, h2.x, fmaf(wa.w, h3.x, fmaf(wb.x, h4.x, fmaf(wb.y, h5.x, -F5L2E)))))));
            e.y = exp2f(fmaf(wa.x, h0.y, fmaf(wa.y, h1.y, fmaf(wa.z, h2.y, fmaf(wa.w, h3.y, fmaf(wb.x, h4.y, fmaf(wb.y, h5.y, -F5L2E)))))));
            e.z = exp2f(fmaf(wa.x, h0.z, fmaf(wa.y, h1.z, fmaf(wa.z, h2.z, fmaf(wa.w, h3.z, fmaf(wb.x, h4.z, fmaf(wb.y, h5.z, -F5L2E)))))));
            e.w = exp2f(fmaf(wa.x, h0.w, fmaf(wa.y, h1.w, fmaf(wa.z, h2.w, fmaf(wa.w, h3.w, fmaf(wb.x, h4.w, fmaf(wb.y, h5.w, -F5L2E)))))));
            E1s[(fy - 1) * ES + tx] = e;
        }
    }
    __syncthreads();

    // ---- Stage CD: rolling E1 hsums -> E2 (min) -> out (log), 4 rows/thread ----
    {
        const int dx = tid & 15;          // vec4 col
        const int sq = tid >> 4;          // 4-row strip
        const int lr0 = 4 * sq;           // lds row of E1 fy=4sq+1
        const bool rT = (by == 0)  && (sq == 0);    // E2 fy=2  (gy=-1)
        const bool rB = (by == 15) && (sq == 15);   // E2 fy=67 (gy=1024)
        const bool cL = (bx == 0)  && (dx == 0);    // E2 col fc=3  (gx=-1)
        const bool cR = (bx == 15) && (dx == 15);   // E2 col fc=68 (gx=1024)

        auto HSUM = [&](int lr, float hs[6]) {
            float4 l = E1s[lr * ES + dx], c = E1s[lr * ES + dx + 1], n = E1s[lr * ES + dx + 2];
            hs[0] = l.z + l.w + c.x;
            hs[1] = l.w + c.x + c.y;
            hs[2] = c.x + c.y + c.z;
            hs[3] = c.y + c.z + c.w;
            hs[4] = c.z + c.w + n.x;
            hs[5] = c.w + n.x + n.y;
        };
        auto E2F = [&](const float* a, const float* bq, const float* c, bool rowOv) -> float4 {
            float e[6];
#pragma unroll
            for (int j = 0; j < 6; ++j) e[j] = fminf(a[j] + bq[j] + c[j], 1.0f);
            if (rowOv) {
#pragma unroll
                for (int j = 0; j < 6; ++j) e[j] = EXPM5;
            }
            if (cL) e[0] = EXPM5;
            if (cR) e[5] = EXPM5;
            return make_float4(e[0] + e[1] + e[2], e[1] + e[2] + e[3],
                               e[2] + e[3] + e[4], e[3] + e[4] + e[5]);
        };
        auto OUTF = [&](float4 a, float4 bq, float4 c) -> float4 {
            float4 o;
            o.x = fmaxf(fminf(fmaf(C02, __log2f(a.x + bq.x + c.x), 1.0f), 1.0f), 0.0f);
            o.y = fmaxf(fminf(fmaf(C02, __log2f(a.y + bq.y + c.y), 1.0f), 1.0f), 0.0f);
            o.z = fmaxf(fminf(fmaf(C02, __log2f(a.z + bq.z + c.z), 1.0f), 1.0f), 0.0f);
            o.w = fmaxf(fminf(fmaf(C02, __log2f(a.w + bq.w + c.w), 1.0f), 1.0f), 0.0f);
            return o;
        };

        float h0[6], h1[6], h2[6], h3[6], h4[6], h5[6], h6[6], h7[6];
        size_t obase = ((size_t)(b * HO + by * TLE + 4 * sq) * WO) + bx * TLE + (dx << 2);

        HSUM(lr0 + 0, h0); HSUM(lr0 + 1, h1); HSUM(lr0 + 2, h2);
        float4 eA = E2F(h0, h1, h2, rT);
        HSUM(lr0 + 3, h3); float4 eB = E2F(h1, h2, h3, false);
        HSUM(lr0 + 4, h4); float4 eC = E2F(h2, h3, h4, false);
        *reinterpret_cast<float4*>(out + obase) = OUTF(eA, eB, eC); obase += WO;
        HSUM(lr0 + 5, h5); float4 eD = E2F(h3, h4, h5, false);
        *reinterpret_cast<float4*>(out + obase) = OUTF(eB, eC, eD); obase += WO;
        HSUM(lr0 + 6, h6); float4 eE = E2F(h4, h5, h6, false);
        *reinterpret_cast<float4*>(out + obase) = OUTF(eC, eD, eE); obase += WO;
        HSUM(lr0 + 7, h7); float4 eF = E2F(h5, h6, h7, rB);
        *reinterpret_cast<float4*>(out + obase) = OUTF(eD, eE, eF);
    }
}

extern "C" void kernel_launch(void* const* d_in, const int* in_sizes, int n_in,
                              void* d_out, int out_size, void* d_ws, size_t ws_size,
                              hipStream_t stream) {
    const float* in = (const float*)d_in[0];
    float* out = (float*)d_out;
    dim3 g(WO / TLE, HO / TLE, B_);   // (16,16,8)
    k_fused<<<g, dim3(256), 0, stream>>>(in, out);
}

// Round 11
// 28.084 us; speedup vs baseline: 6.8743x; 1.0618x over previous
//
#include <hip/hip_runtime.h>

#define B_ 8
#define HI 256
#define WI 256
#define HO 1024
#define WO 1024

#define TLE 64            // output tile 64x64, grid 16x16x8
#define NRS 24            // staged low-res rows/cols
#define SSTR 25           // slice stride (floats)
#define HS 18             // hres row stride (vec4)
#define ES 19             // E1 row stride (vec4)
#define SC (255.0f / 1023.0f)
#define F5L2E 7.2134752f  // 5*log2(e)
#define EXPM5 0.0067379470f
#define GW0 0.27406862f
#define GW1 0.45186276f
#define C02 0.13862944f   // 0.2*ln(2)

__device__ __forceinline__ int basef(int g) {
    int yc = min(max(g, 0), HO - 1);
    return (int)floorf((float)yc * SC) - 2;
}

// Combined conv(gauss3, keys-cubic4) 6-tap. OOB coord -> all-zero weights (so
// the E1 fma chain yields exp2(-F5L2E) = exp(-5) = the zero-pad value).
__device__ __forceinline__ void tap6(int g, int* base_out, float w[6]) {
    int yc = min(max(g, 0), HO - 1);
    int base = basef(g);
#pragma unroll
    for (int s = 0; s < 6; ++s) w[s] = 0.0f;
    if (g >= 0 && g < HO) {
#pragma unroll
        for (int d = -1; d <= 1; ++d) {
            int yd = yc + d;
            if (yd < 0 || yd >= HO) continue;
            float src = (float)yd * SC;
            float fi0 = floorf(src);
            float tt = src - fi0;
            const float a = -0.75f;
            float t1 = tt + 1.0f;
            float c0 = ((a * t1 - 5.0f * a) * t1 + 8.0f * a) * t1 - 4.0f * a;
            float c1 = ((a + 2.0f) * tt - (a + 3.0f)) * tt * tt + 1.0f;
            float u = 1.0f - tt;
            float c2 = ((a + 2.0f) * u - (a + 3.0f)) * u * u + 1.0f;
            float u2 = 2.0f - tt;
            float c3 = ((a * u2 - 5.0f * a) * u2 + 8.0f * a) * u2 - 4.0f * a;
            int s0 = ((int)fi0 - 1) - base;   // in [0,2]
            float gg = (d == 0) ? GW1 : GW0;
            w[s0 + 0] += gg * c0;
            w[s0 + 1] += gg * c1;
            w[s0 + 2] += gg * c2;
            w[s0 + 3] += gg * c3;
        }
    }
    *base_out = base;
}

// pad 6 weights into 8-slot window at shift d (0/1) without dynamic indexing
__device__ __forceinline__ void pad8(const float w[6], int d, float scl, float w8[8]) {
#pragma unroll
    for (int j = 0; j < 8; ++j) {
        float a = (j < 6) ? w[j] : 0.0f;
        float bq = (j >= 1 && j < 7) ? w[j - 1] : 0.0f;
        w8[j] = ((d == 0) ? a : bq) * scl;
    }
}

__device__ __forceinline__ float dot8(float4 a, float4 bq, const float w[8]) {
    float s = a.x * w[0];
    s = fmaf(a.y, w[1], s); s = fmaf(a.z, w[2], s); s = fmaf(a.w, w[3], s);
    s = fmaf(bq.x, w[4], s); s = fmaf(bq.y, w[5], s);
    s = fmaf(bq.z, w[6], s); s = fmaf(bq.w, w[7], s);
    return s;
}

__global__ __launch_bounds__(256, 5) void k_fused(const float* __restrict__ in,
                                                  float* __restrict__ out) {
    __shared__ float4 E1s[68 * ES];                 // 20672 B (slice aliases this)
    __shared__ float4 Hs[NRS * HS];                 // 6912 B
    __shared__ float4 xAw[72], xBw[72];             // 2304 B: 8 padded x-weights/xe
    __shared__ float4 vAw[70], vBw[70];             // 2240 B: 8 padded y-weights/fy (x F5L2E)
    __shared__ int vgb[14], xgb[18];                // 128 B: group window bases
    float* SL = (float*)E1s;

    const int tid = threadIdx.x;
    const int bx = blockIdx.x, by = blockIdx.y, b = blockIdx.z;
    const int gy0 = by * TLE, gx0 = bx * TLE;
    const int rlo = basef(gy0 - 3);
    const int clo = basef(gx0 - 4);

    // ---- Phase 0: tables + sigmoid'd clamped input slice ----
    if (tid < 70) {                       // vertical weights, fy = tid+1
        int fy = tid + 1;
        int base; float w[6];
        tap6(gy0 + fy - 3, &base, w);
        int q = tid / 5;
        int bs = basef(gy0 + (1 + 5 * q) - 3);
        float w8[8];
        pad8(w, base - bs, F5L2E, w8);
        vAw[tid] = make_float4(w8[0], w8[1], w8[2], w8[3]);
        vBw[tid] = make_float4(w8[4], w8[5], w8[6], w8[7]);
    } else if (tid < 84) {
        vgb[tid - 70] = basef(gy0 + (1 + 5 * (tid - 70)) - 3);
    } else if (tid < 102) {
        xgb[tid - 84] = basef(gx0 + 4 * (tid - 84) - 4);
    } else if (tid >= 128 && tid < 200) { // horizontal weights, xe = tid-128
        int xe = tid - 128;
        int base; float w[6];
        tap6(gx0 + xe - 4, &base, w);
        int bs = basef(gx0 + (xe & ~3) - 4);
        float w8[8];
        pad8(w, base - bs, 1.0f, w8);
        xAw[xe] = make_float4(w8[0], w8[1], w8[2], w8[3]);
        xBw[xe] = make_float4(w8[4], w8[5], w8[6], w8[7]);
    }
    {
        const float* pin = in + b * (HI * WI);
        int cc = tid & 31, rr0 = tid >> 5;
        if (cc < NRS) {
            for (int rr = rr0; rr < NRS; rr += 8) {
                int row = min(max(rlo + rr, 0), HI - 1);
                int col = min(max(clo + cc, 0), HI - 1);
                float x = pin[row * WI + col];
                SL[rr * SSTR + cc] = 1.0f / (1.0f + __expf(-x));
            }
        }
    }
    __syncthreads();

    const int ty = tid / HS;          // [0,14) for tid < 252
    const int tx = tid - ty * HS;

    // ---- Stage A: horizontal 8-window 6-tap -> Hs[24][18] ----
    if (tid < 252) {
        int cbg = xgb[tx] - clo;
        int wc[8];
#pragma unroll
        for (int j = 0; j < 8; ++j) wc[j] = min(cbg + j, NRS - 1);
        float xw0[8], xw1[8], xw2[8], xw3[8];
        {
            int xe0 = tx << 2;
            float4 a0 = xAw[xe0 + 0], b0 = xBw[xe0 + 0];
            float4 a1 = xAw[xe0 + 1], b1 = xBw[xe0 + 1];
            float4 a2 = xAw[xe0 + 2], b2 = xBw[xe0 + 2];
            float4 a3 = xAw[xe0 + 3], b3 = xBw[xe0 + 3];
            xw0[0]=a0.x; xw0[1]=a0.y; xw0[2]=a0.z; xw0[3]=a0.w; xw0[4]=b0.x; xw0[5]=b0.y; xw0[6]=b0.z; xw0[7]=b0.w;
            xw1[0]=a1.x; xw1[1]=a1.y; xw1[2]=a1.z; xw1[3]=a1.w; xw1[4]=b1.x; xw1[5]=b1.y; xw1[6]=b1.z; xw1[7]=b1.w;
            xw2[0]=a2.x; xw2[1]=a2.y; xw2[2]=a2.z; xw2[3]=a2.w; xw2[4]=b2.x; xw2[5]=b2.y; xw2[6]=b2.z; xw2[7]=b2.w;
            xw3[0]=a3.x; xw3[1]=a3.y; xw3[2]=a3.z; xw3[3]=a3.w; xw3[4]=b3.x; xw3[5]=b3.y; xw3[6]=b3.z; xw3[7]=b3.w;
        }
        for (int r = ty; r < NRS; r += 14) {
            const float* srow = SL + r * SSTR;
            float wnd[8];
#pragma unroll
            for (int j = 0; j < 8; ++j) wnd[j] = srow[wc[j]];
            float s0 = wnd[0]*xw0[0], s1 = wnd[0]*xw1[0], s2 = wnd[0]*xw2[0], s3 = wnd[0]*xw3[0];
#pragma unroll
            for (int j = 1; j < 8; ++j) {
                s0 = fmaf(wnd[j], xw0[j], s0);
                s1 = fmaf(wnd[j], xw1[j], s1);
                s2 = fmaf(wnd[j], xw2[j], s2);
                s3 = fmaf(wnd[j], xw3[j], s3);
            }
            Hs[r * HS + tx] = make_float4(s0, s1, s2, s3);
        }
    }
    __syncthreads();

    // ---- Stage B: vertical 8-row register window, 5 consecutive fy/thread -> E1s ----
    if (tid < 252) {
        const int q = ty;                  // fy group [1+5q, 5+5q]
        const int rbase = vgb[q] - rlo;
        float4 h[8];
#pragma unroll
        for (int i = 0; i < 8; ++i) h[i] = Hs[min(rbase + i, NRS - 1) * HS + tx];
#pragma unroll
        for (int i = 0; i < 5; ++i) {
            int fy = 1 + 5 * q + i;
            if (fy <= 68) {
                float4 wa = vAw[fy - 1], wb = vBw[fy - 1];
                const float wv[8] = {wa.x, wa.y, wa.z, wa.w, wb.x, wb.y, wb.z, wb.w};
                float ax = -F5L2E, ay = -F5L2E, az = -F5L2E, aw = -F5L2E;
#pragma unroll
                for (int j = 0; j < 8; ++j) {
                    ax = fmaf(wv[j], h[j].x, ax);
                    ay = fmaf(wv[j], h[j].y, ay);
                    az = fmaf(wv[j], h[j].z, az);
                    aw = fmaf(wv[j], h[j].w, aw);
                }
                float4 e;
                e.x = exp2f(ax); e.y = exp2f(ay); e.z = exp2f(az); e.w = exp2f(aw);
                E1s[(fy - 1) * ES + tx] = e;
            }
        }
    }
    __syncthreads();

    // ---- Stage CD: rolling E1 hsums -> E2 (min) -> out (log), 4 rows/thread ----
    {
        const int dx = tid & 15;
        const int sq = tid >> 4;
        const int lr0 = 4 * sq;
        const bool rT = (by == 0)  && (sq == 0);
        const bool rB = (by == 15) && (sq == 15);
        const bool cL = (bx == 0)  && (dx == 0);
        const bool cR = (bx == 15) && (dx == 15);

        auto HSUM = [&](int lr, float hs[6]) {
            float4 l = E1s[lr * ES + dx], c = E1s[lr * ES + dx + 1], n = E1s[lr * ES + dx + 2];
            hs[0] = l.z + l.w + c.x;
            hs[1] = l.w + c.x + c.y;
            hs[2] = c.x + c.y + c.z;
            hs[3] = c.y + c.z + c.w;
            hs[4] = c.z + c.w + n.x;
            hs[5] = c.w + n.x + n.y;
        };
        auto E2F = [&](const float* a, const float* bq, const float* c, bool rowOv) -> float4 {
            float e[6];
#pragma unroll
            for (int j = 0; j < 6; ++j) e[j] = fminf(a[j] + bq[j] + c[j], 1.0f);
            if (rowOv) {
#pragma unroll
                for (int j = 0; j < 6; ++j) e[j] = EXPM5;
            }
            if (cL) e[0] = EXPM5;
            if (cR) e[5] = EXPM5;
            return make_float4(e[0] + e[1] + e[2], e[1] + e[2] + e[3],
                               e[2] + e[3] + e[4], e[3] + e[4] + e[5]);
        };
        auto OUTF = [&](float4 a, float4 bq, float4 c) -> float4 {
            float4 o;
            o.x = fmaxf(fminf(fmaf(C02, __log2f(a.x + bq.x + c.x), 1.0f), 1.0f), 0.0f);
            o.y = fmaxf(fminf(fmaf(C02, __log2f(a.y + bq.y + c.y), 1.0f), 1.0f), 0.0f);
            o.z = fmaxf(fminf(fmaf(C02, __log2f(a.z + bq.z + c.z), 1.0f), 1.0f), 0.0f);
            o.w = fmaxf(fminf(fmaf(C02, __log2f(a.w + bq.w + c.w), 1.0f), 1.0f), 0.0f);
            return o;
        };

        float h0[6], h1[6], h2[6], h3[6], h4[6], h5[6], h6[6], h7[6];
        size_t obase = ((size_t)(b * HO + by * TLE + 4 * sq) * WO) + bx * TLE + (dx << 2);

        HSUM(lr0 + 0, h0); HSUM(lr0 + 1, h1); HSUM(lr0 + 2, h2);
        float4 eA = E2F(h0, h1, h2, rT);
        HSUM(lr0 + 3, h3); float4 eB = E2F(h1, h2, h3, false);
        HSUM(lr0 + 4, h4); float4 eC = E2F(h2, h3, h4, false);
        *reinterpret_cast<float4*>(out + obase) = OUTF(eA, eB, eC); obase += WO;
        HSUM(lr0 + 5, h5); float4 eD = E2F(h3, h4, h5, false);
        *reinterpret_cast<float4*>(out + obase) = OUTF(eB, eC, eD); obase += WO;
        HSUM(lr0 + 6, h6); float4 eE = E2F(h4, h5, h6, false);
        *reinterpret_cast<float4*>(out + obase) = OUTF(eC, eD, eE); obase += WO;
        HSUM(lr0 + 7, h7); float4 eF = E2F(h5, h6, h7, rB);
        *reinterpret_cast<float4*>(out + obase) = OUTF(eD, eE, eF);
    }
}

extern "C" void kernel_launch(void* const* d_in, const int* in_sizes, int n_in,
                              void* d_out, int out_size, void* d_ws, size_t ws_size,
                              hipStream_t stream) {
    const float* in = (const float*)d_in[0];
    float* out = (float*)d_out;
    dim3 g(WO / TLE, HO / TLE, B_);   // (16,16,8)
    k_fused<<<g, dim3(256), 0, stream>>>(in, out);
}

// Round 12
// 24.709 us; speedup vs baseline: 7.8132x; 1.1366x over previous
//
#include <hip/hip_runtime.h>
#include <hip/hip_fp16.h>

#define B_ 8
#define HI 256
#define WI 256
#define HO 1024
#define WO 1024

#define TLE 64            // output tile 64x64, grid 16x16x8
#define NRS 24            // staged low-res rows/cols
#define SSTR 25           // slice stride (floats)
#define HS 18             // hres row stride (vec4)
#define EW 38             // E1 half-row stride in uints (152 B, 72 halfs + pad)
#define SC (255.0f / 1023.0f)
#define F5L2E 7.2134752f  // 5*log2(e)
#define EXPM5 0.0067379470f
#define GW0 0.27406862f
#define GW1 0.45186276f
#define C02 0.13862944f   // 0.2*ln(2)

__device__ __forceinline__ int basef(int g) {
    int yc = min(max(g, 0), HO - 1);
    return (int)floorf((float)yc * SC) - 2;
}

// Combined conv(gauss3, keys-cubic4) 6-tap. OOB coord -> all-zero weights (so
// the E1 fma chain yields exp2(-F5L2E) = exp(-5) = the zero-pad value).
__device__ __forceinline__ void tap6(int g, int* base_out, float w[6]) {
    int yc = min(max(g, 0), HO - 1);
    int base = basef(g);
#pragma unroll
    for (int s = 0; s < 6; ++s) w[s] = 0.0f;
    if (g >= 0 && g < HO) {
#pragma unroll
        for (int d = -1; d <= 1; ++d) {
            int yd = yc + d;
            if (yd < 0 || yd >= HO) continue;
            float src = (float)yd * SC;
            float fi0 = floorf(src);
            float tt = src - fi0;
            const float a = -0.75f;
            float t1 = tt + 1.0f;
            float c0 = ((a * t1 - 5.0f * a) * t1 + 8.0f * a) * t1 - 4.0f * a;
            float c1 = ((a + 2.0f) * tt - (a + 3.0f)) * tt * tt + 1.0f;
            float u = 1.0f - tt;
            float c2 = ((a + 2.0f) * u - (a + 3.0f)) * u * u + 1.0f;
            float u2 = 2.0f - tt;
            float c3 = ((a * u2 - 5.0f * a) * u2 + 8.0f * a) * u2 - 4.0f * a;
            int s0 = ((int)fi0 - 1) - base;   // in [0,2]
            float gg = (d == 0) ? GW1 : GW0;
            w[s0 + 0] += gg * c0;
            w[s0 + 1] += gg * c1;
            w[s0 + 2] += gg * c2;
            w[s0 + 3] += gg * c3;
        }
    }
    *base_out = base;
}

// pad 6 weights into 8-slot window at shift d (0/1) without dynamic indexing
__device__ __forceinline__ void pad8(const float w[6], int d, float scl, float w8[8]) {
#pragma unroll
    for (int j = 0; j < 8; ++j) {
        float a = (j < 6) ? w[j] : 0.0f;
        float bq = (j >= 1 && j < 7) ? w[j - 1] : 0.0f;
        w8[j] = ((d == 0) ? a : bq) * scl;
    }
}

__global__ __launch_bounds__(256, 7) void k_fused(const float* __restrict__ in,
                                                  float* __restrict__ out) {
    __shared__ __align__(16) unsigned int Eu[68 * EW];   // E1 in half, 10336 B (slice aliases)
    __shared__ float4 Hs[NRS * HS];                      // 6912 B
    __shared__ float4 xAw[72], xBw[72];                  // 2304 B
    __shared__ float4 vAw[70], vBw[70];                  // 2240 B
    __shared__ int vgb[14], xgb[18];                     // 128 B  -> 21.9 KB total
    float* SL = (float*)Eu;

    const int tid = threadIdx.x;
    const int bx = blockIdx.x, by = blockIdx.y, b = blockIdx.z;
    const int gy0 = by * TLE, gx0 = bx * TLE;
    const int rlo = basef(gy0 - 3);
    const int clo = basef(gx0 - 4);

    // ---- Phase 0: tables + sigmoid'd clamped input slice ----
    if (tid < 70) {                       // vertical weights, fy = tid+1
        int fy = tid + 1;
        int base; float w[6];
        tap6(gy0 + fy - 3, &base, w);
        int q = tid / 5;
        int bs = basef(gy0 + (1 + 5 * q) - 3);
        float w8[8];
        pad8(w, base - bs, F5L2E, w8);
        vAw[tid] = make_float4(w8[0], w8[1], w8[2], w8[3]);
        vBw[tid] = make_float4(w8[4], w8[5], w8[6], w8[7]);
    } else if (tid < 84) {
        vgb[tid - 70] = basef(gy0 + (1 + 5 * (tid - 70)) - 3);
    } else if (tid < 102) {
        xgb[tid - 84] = basef(gx0 + 4 * (tid - 84) - 4);
    } else if (tid >= 128 && tid < 200) { // horizontal weights, xe = tid-128
        int xe = tid - 128;
        int base; float w[6];
        tap6(gx0 + xe - 4, &base, w);
        int bs = basef(gx0 + (xe & ~3) - 4);
        float w8[8];
        pad8(w, base - bs, 1.0f, w8);
        xAw[xe] = make_float4(w8[0], w8[1], w8[2], w8[3]);
        xBw[xe] = make_float4(w8[4], w8[5], w8[6], w8[7]);
    }
    {
        const float* pin = in + b * (HI * WI);
        int cc = tid & 31, rr0 = tid >> 5;
        if (cc < NRS) {
            for (int rr = rr0; rr < NRS; rr += 8) {
                int row = min(max(rlo + rr, 0), HI - 1);
                int col = min(max(clo + cc, 0), HI - 1);
                float x = pin[row * WI + col];
                SL[rr * SSTR + cc] = 1.0f / (1.0f + __expf(-x));
            }
        }
    }
    __syncthreads();

    const int ty = tid / HS;          // [0,14) for tid < 252
    const int tx = tid - ty * HS;

    // ---- Stage A: horizontal 8-window 6-tap -> Hs[24][18] ----
    if (tid < 252) {
        int cbg = xgb[tx] - clo;
        int wc[8];
#pragma unroll
        for (int j = 0; j < 8; ++j) wc[j] = min(cbg + j, NRS - 1);
        float xw0[8], xw1[8], xw2[8], xw3[8];
        {
            int xe0 = tx << 2;
            float4 a0 = xAw[xe0 + 0], b0 = xBw[xe0 + 0];
            float4 a1 = xAw[xe0 + 1], b1 = xBw[xe0 + 1];
            float4 a2 = xAw[xe0 + 2], b2 = xBw[xe0 + 2];
            float4 a3 = xAw[xe0 + 3], b3 = xBw[xe0 + 3];
            xw0[0]=a0.x; xw0[1]=a0.y; xw0[2]=a0.z; xw0[3]=a0.w; xw0[4]=b0.x; xw0[5]=b0.y; xw0[6]=b0.z; xw0[7]=b0.w;
            xw1[0]=a1.x; xw1[1]=a1.y; xw1[2]=a1.z; xw1[3]=a1.w; xw1[4]=b1.x; xw1[5]=b1.y; xw1[6]=b1.z; xw1[7]=b1.w;
            xw2[0]=a2.x; xw2[1]=a2.y; xw2[2]=a2.z; xw2[3]=a2.w; xw2[4]=b2.x; xw2[5]=b2.y; xw2[6]=b2.z; xw2[7]=b2.w;
            xw3[0]=a3.x; xw3[1]=a3.y; xw3[2]=a3.z; xw3[3]=a3.w; xw3[4]=b3.x; xw3[5]=b3.y; xw3[6]=b3.z; xw3[7]=b3.w;
        }
        for (int r = ty; r < NRS; r += 14) {
            const float* srow = SL + r * SSTR;
            float wnd[8];
#pragma unroll
            for (int j = 0; j < 8; ++j) wnd[j] = srow[wc[j]];
            float s0 = wnd[0]*xw0[0], s1 = wnd[0]*xw1[0], s2 = wnd[0]*xw2[0], s3 = wnd[0]*xw3[0];
#pragma unroll
            for (int j = 1; j < 8; ++j) {
                s0 = fmaf(wnd[j], xw0[j], s0);
                s1 = fmaf(wnd[j], xw1[j], s1);
                s2 = fmaf(wnd[j], xw2[j], s2);
                s3 = fmaf(wnd[j], xw3[j], s3);
            }
            Hs[r * HS + tx] = make_float4(s0, s1, s2, s3);
        }
    }
    __syncthreads();

    // ---- Stage B: vertical 8-row register window -> E1 (half2) rows fy 1..68 ----
    if (tid < 252) {
        const int q = ty;
        const int rbase = vgb[q] - rlo;
        float4 h[8];
#pragma unroll
        for (int i = 0; i < 8; ++i) h[i] = Hs[min(rbase + i, NRS - 1) * HS + tx];
#pragma unroll
        for (int i = 0; i < 5; ++i) {
            int fy = 1 + 5 * q + i;
            if (fy <= 68) {
                float4 wa = vAw[fy - 1], wb = vBw[fy - 1];
                const float wv[8] = {wa.x, wa.y, wa.z, wa.w, wb.x, wb.y, wb.z, wb.w};
                float ax = -F5L2E, ay = -F5L2E, az = -F5L2E, aw = -F5L2E;
#pragma unroll
                for (int j = 0; j < 8; ++j) {
                    ax = fmaf(wv[j], h[j].x, ax);
                    ay = fmaf(wv[j], h[j].y, ay);
                    az = fmaf(wv[j], h[j].z, az);
                    aw = fmaf(wv[j], h[j].w, aw);
                }
                unsigned int p0 = __builtin_bit_cast(unsigned int, __floats2half2_rn(exp2f(ax), exp2f(ay)));
                unsigned int p1 = __builtin_bit_cast(unsigned int, __floats2half2_rn(exp2f(az), exp2f(aw)));
                *reinterpret_cast<uint2*>(&Eu[(fy - 1) * EW + 2 * tx]) = make_uint2(p0, p1);
            }
        }
    }
    __syncthreads();

    // ---- Stage CD: rolling E2 (min) -> out (log), fp16 E1 reads, 4 rows/thread ----
    {
        const int dx = tid & 15;
        const int sq = tid >> 4;
        const int lr0 = 4 * sq;
        const bool rT = (by == 0)  && (sq == 0);
        const bool rB = (by == 15) && (sq == 15);
        const bool cL = (bx == 0)  && (dx == 0);
        const bool cR = (bx == 15) && (dx == 15);

        // HSUM: E1 half row lr, frame half cols [4dx+2 .. 4dx+9] -> 6 sums
        auto HSUM = [&](int lr, float hs[6]) {
            unsigned int ua = Eu[lr * EW + 2 * dx + 1];                                 // halfs 4dx+2,3
            uint2 ub = *reinterpret_cast<const uint2*>(&Eu[lr * EW + 2 * dx + 2]);      // halfs 4dx+4..7
            unsigned int uc = Eu[lr * EW + 2 * dx + 4];                                 // halfs 4dx+8,9
            __half2 A2 = __builtin_bit_cast(__half2, ua);
            __half2 B2 = __builtin_bit_cast(__half2, ub.x);
            __half2 C2 = __builtin_bit_cast(__half2, ub.y);
            __half2 D2 = __builtin_bit_cast(__half2, uc);
            float e0 = __low2float(A2), e1 = __high2float(A2);
            float e2 = __low2float(B2), e3 = __high2float(B2);
            float e4 = __low2float(C2), e5 = __high2float(C2);
            float e6 = __low2float(D2), e7 = __high2float(D2);
            hs[0] = e0 + e1 + e2;
            hs[1] = e1 + e2 + e3;
            hs[2] = e2 + e3 + e4;
            hs[3] = e3 + e4 + e5;
            hs[4] = e4 + e5 + e6;
            hs[5] = e5 + e6 + e7;
        };
        auto E2F = [&](const float* a, const float* bq, const float* c, bool rowOv) -> float4 {
            float e[6];
#pragma unroll
            for (int j = 0; j < 6; ++j) e[j] = fminf(a[j] + bq[j] + c[j], 1.0f);
            if (rowOv) {
#pragma unroll
                for (int j = 0; j < 6; ++j) e[j] = EXPM5;
            }
            if (cL) e[0] = EXPM5;
            if (cR) e[5] = EXPM5;
            return make_float4(e[0] + e[1] + e[2], e[1] + e[2] + e[3],
                               e[2] + e[3] + e[4], e[3] + e[4] + e[5]);
        };
        auto OUTF = [&](float4 a, float4 bq, float4 c) -> float4 {
            float4 o;
            o.x = fmaxf(fminf(fmaf(C02, __log2f(a.x + bq.x + c.x), 1.0f), 1.0f), 0.0f);
            o.y = fmaxf(fminf(fmaf(C02, __log2f(a.y + bq.y + c.y), 1.0f), 1.0f), 0.0f);
            o.z = fmaxf(fminf(fmaf(C02, __log2f(a.z + bq.z + c.z), 1.0f), 1.0f), 0.0f);
            o.w = fmaxf(fminf(fmaf(C02, __log2f(a.w + bq.w + c.w), 1.0f), 1.0f), 0.0f);
            return o;
        };

        float hA[6], hB[6], hC[6], hD[6];
        size_t obase = ((size_t)(b * HO + by * TLE + 4 * sq) * WO) + bx * TLE + (dx << 2);

        HSUM(lr0 + 0, hA); HSUM(lr0 + 1, hB); HSUM(lr0 + 2, hC);
        float4 eA = E2F(hA, hB, hC, rT);
        HSUM(lr0 + 3, hD); float4 eB = E2F(hB, hC, hD, false);
        HSUM(lr0 + 4, hA); float4 eC = E2F(hC, hD, hA, false);
        *reinterpret_cast<float4*>(out + obase) = OUTF(eA, eB, eC); obase += WO;
        HSUM(lr0 + 5, hB); float4 eD = E2F(hD, hA, hB, false);
        *reinterpret_cast<float4*>(out + obase) = OUTF(eB, eC, eD); obase += WO;
        HSUM(lr0 + 6, hC); float4 eE = E2F(hA, hB, hC, false);
        *reinterpret_cast<float4*>(out + obase) = OUTF(eC, eD, eE); obase += WO;
        HSUM(lr0 + 7, hD); float4 eF = E2F(hB, hC, hD, rB);
        *reinterpret_cast<float4*>(out + obase) = OUTF(eD, eE, eF);
    }
}

extern "C" void kernel_launch(void* const* d_in, const int* in_sizes, int n_in,
                              void* d_out, int out_size, void* d_ws, size_t ws_size,
                              hipStream_t stream) {
    const float* in = (const float*)d_in[0];
    float* out = (float*)d_out;
    dim3 g(WO / TLE, HO / TLE, B_);   // (16,16,8)
    k_fused<<<g, dim3(256), 0, stream>>>(in, out);
}